// Round 4
// baseline (257.060 us; speedup 1.0000x reference)
//
#include <hip/hip_runtime.h>
#include <hip/hip_bf16.h>

#define B_ 4
#define T_ 2048
#define E_ 1024
#define H_ 16
#define D_ 64
#define M_ (B_*T_)   // 8192 rows

typedef short bf16x8 __attribute__((ext_vector_type(8)));
typedef float f32x4  __attribute__((ext_vector_type(4)));
typedef float f32x16 __attribute__((ext_vector_type(16)));

__device__ __forceinline__ short f2bf(float f) {
    __hip_bfloat16 h = __float2bfloat16(f);
    return *reinterpret_cast<short*>(&h);
}

__device__ __forceinline__ void async_ld16(const void* g, void* l) {
    __builtin_amdgcn_global_load_lds(
        (const __attribute__((address_space(1))) unsigned int*)g,
        (__attribute__((address_space(3))) unsigned int*)l, 16, 0, 0);
}

// ---------------------------------------------------------------------------
// Prep: fp32 -> bf16 elementwise (x and Wo).
// ---------------------------------------------------------------------------
__global__ void conv_bf16(const float* __restrict__ src, short* __restrict__ dst) {
    const int i = blockIdx.x * 256 + threadIdx.x;
    float4 v = ((const float4*)src)[i];
    short4 o = make_short4(f2bf(v.x), f2bf(v.y), f2bf(v.z), f2bf(v.w));
    ((short4*)dst)[i] = o;
}

// ---------------------------------------------------------------------------
// Prep: bias_pre[b][s] = ((1-mask)*(-3.4e38)) * 1.4427 - 6*1.4427
// (exp2-folded additive bias with static max m=6). mask=1 -> -8.6565.
// ---------------------------------------------------------------------------
__global__ void bias_prep(const float* __restrict__ mask, float* __restrict__ bias) {
    const int i = blockIdx.x * 256 + threadIdx.x;
    float bm = (1.0f - mask[i]) * -3.402823466e38f;   // 0 or -3.4e38
    bias[i] = fmaf(bm, 1.4426950f, -8.6561700f);      // -inf ok (exp2 -> 0)
}

// ---------------------------------------------------------------------------
// Prep: Wq/Wk/Wv [H][E][D] fp32 -> Wt [3*1024 n][1024 e] bf16, n = h*64+d.
// ---------------------------------------------------------------------------
__global__ void wtrans(const float* __restrict__ Wq,
                       const float* __restrict__ Wk,
                       const float* __restrict__ Wv,
                       short* __restrict__ Wt) {
    const int which = blockIdx.z;
    const float* __restrict__ W = (which == 0) ? Wq : (which == 1) ? Wk : Wv;
    const int h  = blockIdx.y;
    const int e0 = blockIdx.x * 64;

    __shared__ float tile[64][65];
    const int tid = threadIdx.x;

#pragma unroll
    for (int r = 0; r < 4; ++r) {
        int lin = tid + r * 256;
        int er = lin >> 4, c4 = (lin & 15) * 4;
        float4 v = *(const float4*)(W + ((size_t)h * E_ + e0 + er) * D_ + c4);
        tile[er][c4 + 0] = v.x; tile[er][c4 + 1] = v.y;
        tile[er][c4 + 2] = v.z; tile[er][c4 + 3] = v.w;
    }
    __syncthreads();
#pragma unroll
    for (int r = 0; r < 4; ++r) {
        int lin = tid + r * 256;
        int dr = lin >> 4, j4 = (lin & 15) * 4;
        short4 o = make_short4(f2bf(tile[j4 + 0][dr]), f2bf(tile[j4 + 1][dr]),
                               f2bf(tile[j4 + 2][dr]), f2bf(tile[j4 + 3][dr]));
        *(short4*)(Wt + ((size_t)which * 1024 + h * 64 + dr) * E_ + e0 + j4) = o;
    }
}

// ---------------------------------------------------------------------------
// MFMA GEMM — m97 fragment layout, NEW pipelined schedule (R4):
// 3-buffer LDS, depth-2 prefetch, counted vmcnt, ONE s_barrier per K-step.
//   iter kt: vmcnt(4) [tile kt landed, kt+1 in flight] -> s_barrier ->
//            STAGE(kt+2) -> ds_read buf[kt%3] -> 16 MFMA (setprio 1).
// Race: STAGE(kt+2) writes buf[(kt-1)%3]; all waves passed barrier kt, which
// they could only do after consuming their iter-(kt-1) ds_reads. Safe.
// LDS 48KB -> 3 blocks/CU (12 waves/CU).
//
// MODE 0: C -> q/k bf16 [B,H,T,D] scatter; q PRE-SCALED by 1/sqrt(D)*log2e.
//         V directly TRANSPOSED [B,H,D,T].
// MODE 1: C -> fp32 [M][E] + bias.
// ---------------------------------------------------------------------------
template <int MODE>
__global__ __launch_bounds__(256) void mfma_gemm(
        const short* __restrict__ A,
        const short* __restrict__ Bt,
        short* __restrict__ qo, short* __restrict__ ko, short* __restrict__ vo,
        float* __restrict__ Cout, const float* __restrict__ bo) {
    __shared__ __align__(16) short As[3][128 * 32];
    __shared__ __align__(16) short Bs[3][128 * 32];

    const int tid  = threadIdx.x;
    const int wave = tid >> 6, lane = tid & 63;
    const int c = lane & 15, quad = lane >> 4;
    const int wm = wave >> 1, wn = wave & 1;
    const int m0 = blockIdx.x * 128;
    const int n0 = blockIdx.y * 128;

    int rowS[2], kgS[2];
#pragma unroll
    for (int r = 0; r < 2; ++r) {
        int p = r * 256 + wave * 64 + lane;
        rowS[r] = p >> 2;
        kgS[r]  = (p & 3) ^ ((rowS[r] >> 1) & 3);
    }

    f32x4 acc[4][4] = {};

#define STAGE(kt2, bu) do {                                                  \
        const int _k0 = (kt2) * 32;                                          \
        _Pragma("unroll")                                                    \
        for (int r = 0; r < 2; ++r) {                                        \
            async_ld16(A  + (size_t)(m0 + rowS[r]) * 1024 + _k0 + kgS[r] * 8,\
                       &As[bu][(r * 256 + wave * 64) * 8]);                  \
            async_ld16(Bt + (size_t)(n0 + rowS[r]) * 1024 + _k0 + kgS[r] * 8,\
                       &Bs[bu][(r * 256 + wave * 64) * 8]);                  \
        }                                                                    \
    } while (0)

    STAGE(0, 0);
    STAGE(1, 1);

    int bi = 0, wbuf = 2;
    for (int kt = 0; kt < 32; ++kt) {
        if (kt < 31) asm volatile("s_waitcnt vmcnt(4)" ::: "memory");
        else         asm volatile("s_waitcnt vmcnt(0)" ::: "memory");
        __builtin_amdgcn_s_barrier();              // tile kt landed everywhere
        if (kt + 2 < 32) STAGE(kt + 2, wbuf);

        const short* __restrict__ as = As[bi];
        const short* __restrict__ bs = Bs[bi];
        bf16x8 af[4], bf[4];
#pragma unroll
        for (int mi = 0; mi < 4; ++mi) {
            int row = wm * 64 + mi * 16 + c;
            int pos = row * 4 + (quad ^ ((row >> 1) & 3));
            af[mi] = *(const bf16x8*)(as + pos * 8);
        }
#pragma unroll
        for (int ni = 0; ni < 4; ++ni) {
            int row = wn * 64 + ni * 16 + c;
            int pos = row * 4 + (quad ^ ((row >> 1) & 3));
            bf[ni] = *(const bf16x8*)(bs + pos * 8);
        }
        __builtin_amdgcn_s_setprio(1);
#pragma unroll
        for (int mi = 0; mi < 4; ++mi)
#pragma unroll
            for (int ni = 0; ni < 4; ++ni)
                acc[mi][ni] = __builtin_amdgcn_mfma_f32_16x16x32_bf16(
                    af[mi], bf[ni], acc[mi][ni], 0, 0, 0);
        __builtin_amdgcn_s_setprio(0);

        bi = (bi == 2) ? 0 : bi + 1;
        wbuf = (wbuf == 2) ? 0 : wbuf + 1;
    }
#undef STAGE

    if (MODE == 0) {
        const int which = n0 >> 10;
        const int nb = n0 & 1023;
        if (which == 2) {
            // V: store transposed [b,h,d,t], vectorized short4 along t
#pragma unroll
            for (int mi = 0; mi < 4; ++mi) {
                const int m = m0 + wm * 64 + mi * 16 + quad * 4;
                const int b = m >> 11, t = m & 2047;
#pragma unroll
                for (int ni = 0; ni < 4; ++ni) {
                    const int n = nb + wn * 64 + ni * 16 + c;
                    const int h = n >> 6, d = n & 63;
                    short4 s4 = make_short4(f2bf(acc[mi][ni][0]), f2bf(acc[mi][ni][1]),
                                            f2bf(acc[mi][ni][2]), f2bf(acc[mi][ni][3]));
                    *(short4*)(vo + (((size_t)b * H_ + h) * D_ + d) * T_ + t) = s4;
                }
            }
        } else {
            short* __restrict__ outp = (which == 0) ? qo : ko;
            // q pre-scaled by 1/sqrt(D)*log2(e) so flash uses exp2(S + bias)
            const float sc = (which == 0) ? 0.18033688f : 1.0f;
#pragma unroll
            for (int mi = 0; mi < 4; ++mi) {
#pragma unroll
                for (int i = 0; i < 4; ++i) {
                    const int m = m0 + wm * 64 + mi * 16 + quad * 4 + i;
                    const int b = m >> 11, t = m & 2047;
#pragma unroll
                    for (int ni = 0; ni < 4; ++ni) {
                        const int n = nb + wn * 64 + ni * 16 + c;
                        const int h = n >> 6, d = n & 63;
                        outp[(((size_t)b * H_ + h) * T_ + t) * D_ + d] =
                            f2bf(acc[mi][ni][i] * sc);
                    }
                }
            }
        }
    } else {
#pragma unroll
        for (int mi = 0; mi < 4; ++mi) {
#pragma unroll
            for (int i = 0; i < 4; ++i) {
                const int m = m0 + wm * 64 + mi * 16 + quad * 4 + i;
#pragma unroll
                for (int ni = 0; ni < 4; ++ni) {
                    const int n = n0 + wn * 64 + ni * 16 + c;
                    Cout[(size_t)m * E_ + n] = acc[mi][ni][i] + bo[n];
                }
            }
        }
    }
}

// ---------------------------------------------------------------------------
// Flash attention v6: 8-wave (512-thread) blocks, all waves sharing one
// 256-row q block (kb). Each staged K/V tile is consumed by 8 waves.
// 4-buffer depth-2 prefetch, ONE barrier per iteration, counted vmcnt (T3/T4).
// Softmax in-register (T12: v_cvt_pk_bf16_f32 + permlane32_swap), T5 setprio.
// ---------------------------------------------------------------------------
__global__ __launch_bounds__(512, 4) void flash_attn6(
        const short* __restrict__ qg,
        const short* __restrict__ kg,
        const short* __restrict__ vtg,
        const float* __restrict__ biasg,
        short* __restrict__ attn) {
    const int h = blockIdx.x, b = blockIdx.y;
    const int kb = 7 - blockIdx.z;                 // 256-row q block, heavy first
    const int tid  = threadIdx.x;
    const int wave = tid >> 6, lane = tid & 63;
    const int ln = lane & 31, hi = lane >> 5;
    const int q0w = kb * 256 + wave * 32;          // this wave's 32 q rows
    const int mytile = 8 * kb + wave;              // wave's diagonal tile
    const int nt = 8 * kb + 8;

    __shared__ __align__(16) char lds[41984];

    const size_t bh = (size_t)b * H_ + h;
    const short* qbh  = qg  + bh * (size_t)T_ * D_;
    const short* kbh  = kg  + bh * (size_t)T_ * D_;
    const short* vtbh = vtg + bh * (size_t)D_ * T_;
    const float* biasb = biasg + (size_t)b * T_;

    // staging coords: one 16B chunk per thread per tile
    const bool stK = (tid < 256);                  // wave-uniform
    const int t2 = tid & 255;
    const int ks = t2 >> 3, kgs = (t2 & 7) ^ (ks & 7);        // K row / src chunk
    const int vd = t2 >> 2, vgs = ((t2 & 3) - (vd >> 1)) & 3; // V row / src chunk

    // swizzled LDS read offsets (add (tt&3)*8192 at use)
    int kaddr[4];
#pragma unroll
    for (int kc = 0; kc < 4; ++kc)
        kaddr[kc] = ln * 128 + ((((kc << 1) + hi) ^ (ln & 7)) << 4);
    int vaddr[4];                                  // [dh*2 + kc2]
#pragma unroll
    for (int dh = 0; dh < 2; ++dh)
#pragma unroll
        for (int kc2 = 0; kc2 < 2; ++kc2) {
            int d = dh * 32 + ln;
            vaddr[dh * 2 + kc2] =
                4096 + d * 64 + (((((kc2 << 1) + hi) + (d >> 1)) & 3) << 4);
        }

    // Q fragments (B operand of S^T): col=q=ln, k = kc*16 + hi*8 + e
    bf16x8 qf[4];
#pragma unroll
    for (int kc = 0; kc < 4; ++kc)
        qf[kc] = *(const bf16x8*)(qbh + (size_t)(q0w + ln) * D_ + kc * 16 + hi * 8);

    // stage bias[0..2047] -> LDS once (8KB: 512 threads x 16B)
    async_ld16(biasb + ((wave << 6) + lane) * 4, lds + 32768 + wave * 1024);

#define STAGE_T(tt2) do {                                                   \
        const int _s0 = (tt2) << 5;                                         \
        const int _bb = ((tt2) & 3) * 8192;                                 \
        if (stK) async_ld16(kbh + (size_t)(_s0 + ks) * D_ + (kgs << 3),     \
                            lds + _bb + (wave & 3) * 1024);                 \
        else     async_ld16(vtbh + (size_t)vd * T_ + _s0 + (vgs << 3),      \
                            lds + _bb + 4096 + (wave & 3) * 1024);          \
    } while (0)

    STAGE_T(0);
    STAGE_T(1);

    f32x16 O0 = {}, O1 = {};
    float lacc = 0.0f;

    for (int tt = 0; tt < nt; ++tt) {
        if (tt + 2 < nt) STAGE_T(tt + 2);
        const int rem = nt - 1 - tt;               // staged tiles beyond tt
        if (rem >= 2)      asm volatile("s_waitcnt vmcnt(2)" ::: "memory");
        else if (rem == 1) asm volatile("s_waitcnt vmcnt(1)" ::: "memory");
        else               asm volatile("s_waitcnt vmcnt(0)" ::: "memory");
        __builtin_amdgcn_s_barrier();              // tile tt landed everywhere

        if (tt <= mytile) {
            const int s0 = tt << 5;
            const int bb = (tt & 3) * 8192;

            // bias for the 16 s-rows (broadcast ds_read, uniform addr per hi)
            f32x4 b4[4];
#pragma unroll
            for (int g = 0; g < 4; ++g)
                b4[g] = *(const f32x4*)(lds + 32768 + (s0 + g * 8 + hi * 4) * 4);

            // S^T = K . Q^T  (A=K from LDS, B=Q regs); q pre-scaled
            f32x16 S = {};
            __builtin_amdgcn_s_setprio(1);
#pragma unroll
            for (int kc = 0; kc < 4; ++kc) {
                bf16x8 ka = *(const bf16x8*)(lds + bb + kaddr[kc]);
                S = __builtin_amdgcn_mfma_f32_32x32x16_bf16(ka, qf[kc], S, 0, 0, 0);
            }
            __builtin_amdgcn_s_setprio(0);

            float p[16];
#pragma unroll
            for (int r = 0; r < 16; ++r) {
                float bb2 = ((const float*)&b4[r >> 2])[r & 3];
                p[r] = __builtin_amdgcn_exp2f(S[r] + bb2);
            }
            if (tt == mytile) {                    // causal mask on diagonal
#pragma unroll
                for (int r = 0; r < 16; ++r)
                    if (((r & 3) + ((r >> 2) << 3) + (hi << 2)) > ln)
                        p[r] = 0.0f;
            }
            // l partial (tree)
            {
                float t0 = (p[0] + p[1]) + (p[2] + p[3]);
                float t1 = (p[4] + p[5]) + (p[6] + p[7]);
                float t2s = (p[8] + p[9]) + (p[10] + p[11]);
                float t3 = (p[12] + p[13]) + (p[14] + p[15]);
                lacc += (t0 + t1) + (t2s + t3);
            }

            // pack to bf16 (HW cvt_pk) + permlane32_swap -> PV A-frags (T12)
            unsigned int u0, u1, u2, u3, u4, u5, u6, u7;
            asm("v_cvt_pk_bf16_f32 %0, %1, %2" : "=v"(u0) : "v"(p[0]),  "v"(p[1]));
            asm("v_cvt_pk_bf16_f32 %0, %1, %2" : "=v"(u1) : "v"(p[2]),  "v"(p[3]));
            asm("v_cvt_pk_bf16_f32 %0, %1, %2" : "=v"(u2) : "v"(p[4]),  "v"(p[5]));
            asm("v_cvt_pk_bf16_f32 %0, %1, %2" : "=v"(u3) : "v"(p[6]),  "v"(p[7]));
            asm("v_cvt_pk_bf16_f32 %0, %1, %2" : "=v"(u4) : "v"(p[8]),  "v"(p[9]));
            asm("v_cvt_pk_bf16_f32 %0, %1, %2" : "=v"(u5) : "v"(p[10]), "v"(p[11]));
            asm("v_cvt_pk_bf16_f32 %0, %1, %2" : "=v"(u6) : "v"(p[12]), "v"(p[13]));
            asm("v_cvt_pk_bf16_f32 %0, %1, %2" : "=v"(u7) : "v"(p[14]), "v"(p[15]));
            asm("v_permlane32_swap_b32 %0, %1" : "+v"(u0), "+v"(u2));
            asm("v_permlane32_swap_b32 %0, %1" : "+v"(u1), "+v"(u3));
            asm("v_permlane32_swap_b32 %0, %1" : "+v"(u4), "+v"(u6));
            asm("v_permlane32_swap_b32 %0, %1" : "+v"(u5), "+v"(u7));
            union { unsigned int w[4]; bf16x8 v; } pa0, pa1;
            pa0.w[0] = u0; pa0.w[1] = u1; pa0.w[2] = u2; pa0.w[3] = u3;
            pa1.w[0] = u4; pa1.w[1] = u5; pa1.w[2] = u6; pa1.w[3] = u7;

            // O += P . V  (B=V^T slices from LDS)
            bf16x8 v00 = *(const bf16x8*)(lds + bb + vaddr[0]);
            bf16x8 v01 = *(const bf16x8*)(lds + bb + vaddr[1]);
            bf16x8 v10 = *(const bf16x8*)(lds + bb + vaddr[2]);
            bf16x8 v11 = *(const bf16x8*)(lds + bb + vaddr[3]);
            __builtin_amdgcn_s_setprio(1);
            O0 = __builtin_amdgcn_mfma_f32_32x32x16_bf16(pa0.v, v00, O0, 0, 0, 0);
            O0 = __builtin_amdgcn_mfma_f32_32x32x16_bf16(pa1.v, v01, O0, 0, 0, 0);
            O1 = __builtin_amdgcn_mfma_f32_32x32x16_bf16(pa0.v, v10, O1, 0, 0, 0);
            O1 = __builtin_amdgcn_mfma_f32_32x32x16_bf16(pa1.v, v11, O1, 0, 0, 0);
            __builtin_amdgcn_s_setprio(0);
        }
    }
#undef STAGE_T

    // ---- epilogue: combine l across hi-halves, normalize, store -----------
    unsigned int la = __float_as_uint(lacc), lb2 = la;
    asm("v_permlane32_swap_b32 %0, %1" : "+v"(la), "+v"(lb2));
    const float ltot = __uint_as_float(la) + __uint_as_float(lb2);

    float* lsh = (float*)(lds + 40960) + wave * 32;
    if (hi == 0) lsh[ln] = 1.0f / ltot;
    __syncthreads();

    short* ab = attn + (size_t)b * T_ * E_ + h * D_;
#pragma unroll
    for (int r = 0; r < 16; ++r) {
        const int qrow = (r & 3) + ((r >> 2) << 3) + (hi << 2);
        const float iv = lsh[qrow];
        const size_t base = (size_t)(q0w + qrow) * E_;
        ab[base + ln]      = f2bf(O0[r] * iv);
        ab[base + 32 + ln] = f2bf(O1[r] * iv);
    }
}

// ---------------------------------------------------------------------------
extern "C" void kernel_launch(void* const* d_in, const int* in_sizes, int n_in,
                              void* d_out, int out_size, void* d_ws, size_t ws_size,
                              hipStream_t stream) {
    const float* x    = (const float*)d_in[0];
    const float* mask = (const float*)d_in[1];
    const float* Wq   = (const float*)d_in[2];
    const float* Wk   = (const float*)d_in[3];
    const float* Wv   = (const float*)d_in[4];
    const float* Wo   = (const float*)d_in[5];
    const float* bo   = (const float*)d_in[6];
    float* out        = (float*)d_out;

    const size_t S = (size_t)M_ * E_;              // 8.4M elems
    char* ws = (char*)d_ws;
    short* xb   = (short*)ws;                      // bf16 x; reused as attn
    short* qb   = (short*)(ws + S * 2);
    short* kb   = (short*)(ws + S * 4);
    short* vtb  = (short*)(ws + S * 6);            // V stored transposed by MODE0
    short* Wt   = (short*)(ws + S * 8);
    short* Wob  = (short*)(ws + S * 8 + (size_t)3 * 1024 * 1024 * 2);
    float* bias = (float*)(ws + S * 8 + (size_t)4 * 1024 * 1024 * 2);
    short* attnb = xb;

    conv_bf16<<<dim3(M_ * E_ / 1024), 256, 0, stream>>>(x, xb);
    conv_bf16<<<dim3(E_ * E_ / 1024), 256, 0, stream>>>(Wo, Wob);
    wtrans<<<dim3(E_ / 64, H_, 3), 256, 0, stream>>>(Wq, Wk, Wv, Wt);
    bias_prep<<<dim3(B_ * T_ / 256), 256, 0, stream>>>(mask, bias);

    mfma_gemm<0><<<dim3(M_ / 128, 3 * E_ / 128), 256, 0, stream>>>(
        xb, Wt, qb, kb, vtb, nullptr, nullptr);

    flash_attn6<<<dim3(H_, B_, 8), 512, 0, stream>>>(qb, kb, vtb, bias, attnb);

    mfma_gemm<1><<<dim3(M_ / 128, E_ / 128), 256, 0, stream>>>(
        attnb, Wob, nullptr, nullptr, nullptr, out, bo);
}

// Round 5
// 251.996 us; speedup vs baseline: 1.0201x; 1.0201x over previous
//
#include <hip/hip_runtime.h>
#include <hip/hip_bf16.h>

#define B_ 4
#define T_ 2048
#define E_ 1024
#define H_ 16
#define D_ 64
#define M_ (B_*T_)   // 8192 rows

typedef short bf16x8 __attribute__((ext_vector_type(8)));
typedef float f32x4  __attribute__((ext_vector_type(4)));
typedef float f32x16 __attribute__((ext_vector_type(16)));

__device__ __forceinline__ short f2bf(float f) {
    __hip_bfloat16 h = __float2bfloat16(f);
    return *reinterpret_cast<short*>(&h);
}

__device__ __forceinline__ void async_ld16(const void* g, void* l) {
    __builtin_amdgcn_global_load_lds(
        (const __attribute__((address_space(1))) unsigned int*)g,
        (__attribute__((address_space(3))) unsigned int*)l, 16, 0, 0);
}

// ---------------------------------------------------------------------------
// Prep: fp32 -> bf16 elementwise (x and Wo).
// ---------------------------------------------------------------------------
__global__ void conv_bf16(const float* __restrict__ src, short* __restrict__ dst) {
    const int i = blockIdx.x * 256 + threadIdx.x;
    float4 v = ((const float4*)src)[i];
    short4 o = make_short4(f2bf(v.x), f2bf(v.y), f2bf(v.z), f2bf(v.w));
    ((short4*)dst)[i] = o;
}

// ---------------------------------------------------------------------------
// Prep: bias_pre[b][s] = ((1-mask)*(-3.4e38)) * 1.4427 - 6*1.4427
// (exp2-folded additive bias with static max m=6). mask=1 -> -8.6565.
// ---------------------------------------------------------------------------
__global__ void bias_prep(const float* __restrict__ mask, float* __restrict__ bias) {
    const int i = blockIdx.x * 256 + threadIdx.x;
    float bm = (1.0f - mask[i]) * -3.402823466e38f;   // 0 or -3.4e38
    bias[i] = fmaf(bm, 1.4426950f, -8.6561700f);      // -inf ok (exp2 -> 0)
}

// ---------------------------------------------------------------------------
// Prep: Wq/Wk/Wv [H][E][D] fp32 -> Wt [3*1024 n][1024 e] bf16, n = h*64+d.
// ---------------------------------------------------------------------------
__global__ void wtrans(const float* __restrict__ Wq,
                       const float* __restrict__ Wk,
                       const float* __restrict__ Wv,
                       short* __restrict__ Wt) {
    const int which = blockIdx.z;
    const float* __restrict__ W = (which == 0) ? Wq : (which == 1) ? Wk : Wv;
    const int h  = blockIdx.y;
    const int e0 = blockIdx.x * 64;

    __shared__ float tile[64][65];
    const int tid = threadIdx.x;

#pragma unroll
    for (int r = 0; r < 4; ++r) {
        int lin = tid + r * 256;
        int er = lin >> 4, c4 = (lin & 15) * 4;
        float4 v = *(const float4*)(W + ((size_t)h * E_ + e0 + er) * D_ + c4);
        tile[er][c4 + 0] = v.x; tile[er][c4 + 1] = v.y;
        tile[er][c4 + 2] = v.z; tile[er][c4 + 3] = v.w;
    }
    __syncthreads();
#pragma unroll
    for (int r = 0; r < 4; ++r) {
        int lin = tid + r * 256;
        int dr = lin >> 4, j4 = (lin & 15) * 4;
        short4 o = make_short4(f2bf(tile[j4 + 0][dr]), f2bf(tile[j4 + 1][dr]),
                               f2bf(tile[j4 + 2][dr]), f2bf(tile[j4 + 3][dr]));
        *(short4*)(Wt + ((size_t)which * 1024 + h * 64 + dr) * E_ + e0 + j4) = o;
    }
}

// ---------------------------------------------------------------------------
// MFMA GEMM v2 (R5): phase-split counted-vmcnt schedule (T3+T4).
// BM=256, BN=128, BK=64, 8 waves (4M x 2N, per-wave 64x64 = same fragment
// geometry as the verified 128^2 kernel). 3 K-tile LDS buffers (144 KiB),
// prefetch distance 2 K-tiles, vmcnt(6) once per K-tile (never 0 mid-loop).
//
// Per K-tile k (2 phases):
//  ph0: ds a_[4][2] (8 b128) + b_[0..1][2] (4)   | stage units 0-3 of k+2
//       barrier ; 16 MFMA (ni 0,1) ; barrier
//  ph1: ds b_[2..3][2] (4)                       | stage units 4-5 of k+2
//       vmcnt(6) ; barrier ; 16 MFMA (ni 2,3) ; barrier
// Race: stage(k+2) -> buf[(k+2)%3]; its readers (K-tile k-1) finished before
// the k-1 -> k boundary barrier, which precedes any stage issue. Data-ready:
// vmcnt(6)+barrier at k-1 ph1 drains K-tile k's 6 loads block-wide. Tail:
// k=14 vmcnt(0) (drains k=15), k=15 stages nothing.
//
// Buffer layout (48KB each): A[256][64] bf16 at +0, B[128][64] at +32768.
// 16B-chunk XOR swizzle g = src_chunk ^ (row&7) (involution, both sides).
//
// MODE 0: C -> q/k bf16 [B,H,T,D] scatter; q PRE-SCALED by 1/sqrt(D)*log2e.
//         V directly TRANSPOSED [B,H,D,T].  Grid (32, 24).
// MODE 1: C -> fp32 [M][E] + bias.          Grid (32, 8).
// ---------------------------------------------------------------------------
template <int MODE>
__global__ __launch_bounds__(512, 2) void mfma_gemm(
        const short* __restrict__ A,
        const short* __restrict__ Bt,
        short* __restrict__ qo, short* __restrict__ ko, short* __restrict__ vo,
        float* __restrict__ Cout, const float* __restrict__ bo) {
    __shared__ __align__(16) char lds[3 * 49152];   // 144 KiB

    const int tid  = threadIdx.x;
    const int wave = tid >> 6, lane = tid & 63;
    const int c = lane & 15, quad = lane >> 4;
    const int wm = wave >> 1, wn = wave & 1;        // 4M x 2N
    const int m0 = blockIdx.x * 256;
    const int n0 = blockIdx.y * 128;

    // staging coords: unit u (8KB = 64 rows x 128B); thread slot = tid
    const int rr = tid >> 3;                        // row within unit [0,64)
    const int cc = (tid & 7) ^ (rr & 7);            // source 16B chunk

    // fragment read byte-offsets within a buffer (ks toggles via ^64)
    int aoff[4], boff[4];
#pragma unroll
    for (int mi = 0; mi < 4; ++mi) {
        int row = wm * 64 + mi * 16 + c;
        aoff[mi] = row * 128 + ((quad ^ (row & 7)) << 4);
    }
#pragma unroll
    for (int ni = 0; ni < 4; ++ni) {
        int row = wn * 64 + ni * 16 + c;
        boff[ni] = 32768 + row * 128 + ((quad ^ (row & 7)) << 4);
    }

    f32x4 acc[4][4] = {};

#define STGU(bufb, k0v, u) do {                                              \
        const short* _s = ((u) < 4) ? A : Bt;                                \
        const int _b0 = ((u) < 4) ? (m0 + (u) * 64) : (n0 + ((u) - 4) * 64); \
        const int _do = ((u) < 4) ? ((u) * 8192) : (32768 + ((u) - 4) * 8192);\
        async_ld16(_s + (size_t)(_b0 + rr) * 1024 + (k0v) + cc * 8,          \
                   lds + (bufb) + _do + wave * 1024);                        \
    } while (0)

    // prologue: stage K-tiles 0 and 1 (6 loads each)
#pragma unroll
    for (int u = 0; u < 6; ++u) STGU(0, 0, u);
#pragma unroll
    for (int u = 0; u < 6; ++u) STGU(49152, 64, u);
    asm volatile("s_waitcnt vmcnt(6)" ::: "memory");   // K-tile 0 landed
    __builtin_amdgcn_s_barrier();

    int rbase = 0;
#pragma unroll 1
    for (int k = 0; k < 16; ++k) {
        const char* rb = lds + rbase;
        const int wbase = (rbase == 0) ? 98304 : rbase - 49152;
        const int kw = (k + 2) * 64;

        // ---- phase 0 ----
        bf16x8 a_[4][2], b01[2][2];
#pragma unroll
        for (int mi = 0; mi < 4; ++mi)
#pragma unroll
            for (int ks = 0; ks < 2; ++ks)
                a_[mi][ks] = *(const bf16x8*)(rb + (aoff[mi] ^ (ks << 6)));
#pragma unroll
        for (int ni = 0; ni < 2; ++ni)
#pragma unroll
            for (int ks = 0; ks < 2; ++ks)
                b01[ni][ks] = *(const bf16x8*)(rb + (boff[ni] ^ (ks << 6)));
        if (k < 14) {
            STGU(wbase, kw, 0); STGU(wbase, kw, 1);
            STGU(wbase, kw, 2); STGU(wbase, kw, 3);
        }
        __builtin_amdgcn_s_barrier();
        __builtin_amdgcn_s_setprio(1);
#pragma unroll
        for (int mi = 0; mi < 4; ++mi)
#pragma unroll
            for (int ni = 0; ni < 2; ++ni)
#pragma unroll
                for (int ks = 0; ks < 2; ++ks)
                    acc[mi][ni] = __builtin_amdgcn_mfma_f32_16x16x32_bf16(
                        a_[mi][ks], b01[ni][ks], acc[mi][ni], 0, 0, 0);
        __builtin_amdgcn_s_setprio(0);
        __builtin_amdgcn_s_barrier();

        // ---- phase 1 ----
        bf16x8 b23[2][2];
#pragma unroll
        for (int ni = 0; ni < 2; ++ni)
#pragma unroll
            for (int ks = 0; ks < 2; ++ks)
                b23[ni][ks] = *(const bf16x8*)(rb + (boff[2 + ni] ^ (ks << 6)));
        if (k < 14) { STGU(wbase, kw, 4); STGU(wbase, kw, 5); }
        if (k < 14)       asm volatile("s_waitcnt vmcnt(6)" ::: "memory");
        else if (k == 14) asm volatile("s_waitcnt vmcnt(0)" ::: "memory");
        __builtin_amdgcn_s_barrier();
        __builtin_amdgcn_s_setprio(1);
#pragma unroll
        for (int mi = 0; mi < 4; ++mi)
#pragma unroll
            for (int ni = 0; ni < 2; ++ni)
#pragma unroll
                for (int ks = 0; ks < 2; ++ks)
                    acc[mi][2 + ni] = __builtin_amdgcn_mfma_f32_16x16x32_bf16(
                        a_[mi][ks], b23[ni][ks], acc[mi][2 + ni], 0, 0, 0);
        __builtin_amdgcn_s_setprio(0);
        __builtin_amdgcn_s_barrier();

        rbase = (rbase == 98304) ? 0 : rbase + 49152;
    }
#undef STGU

    if (MODE == 0) {
        const int which = n0 >> 10;
        const int nb = n0 & 1023;
        if (which == 2) {
            // V: store transposed [b,h,d,t], vectorized short4 along t
#pragma unroll
            for (int mi = 0; mi < 4; ++mi) {
                const int m = m0 + wm * 64 + mi * 16 + quad * 4;
                const int b = m >> 11, t = m & 2047;
#pragma unroll
                for (int ni = 0; ni < 4; ++ni) {
                    const int n = nb + wn * 64 + ni * 16 + c;
                    const int h = n >> 6, d = n & 63;
                    short4 s4 = make_short4(f2bf(acc[mi][ni][0]), f2bf(acc[mi][ni][1]),
                                            f2bf(acc[mi][ni][2]), f2bf(acc[mi][ni][3]));
                    *(short4*)(vo + (((size_t)b * H_ + h) * D_ + d) * T_ + t) = s4;
                }
            }
        } else {
            short* __restrict__ outp = (which == 0) ? qo : ko;
            // q pre-scaled by 1/sqrt(D)*log2(e) so flash uses exp2(S + bias)
            const float sc = (which == 0) ? 0.18033688f : 1.0f;
#pragma unroll
            for (int mi = 0; mi < 4; ++mi) {
#pragma unroll
                for (int i = 0; i < 4; ++i) {
                    const int m = m0 + wm * 64 + mi * 16 + quad * 4 + i;
                    const int b = m >> 11, t = m & 2047;
#pragma unroll
                    for (int ni = 0; ni < 4; ++ni) {
                        const int n = nb + wn * 64 + ni * 16 + c;
                        const int h = n >> 6, d = n & 63;
                        outp[(((size_t)b * H_ + h) * T_ + t) * D_ + d] =
                            f2bf(acc[mi][ni][i] * sc);
                    }
                }
            }
        }
    } else {
#pragma unroll
        for (int mi = 0; mi < 4; ++mi) {
#pragma unroll
            for (int i = 0; i < 4; ++i) {
                const int m = m0 + wm * 64 + mi * 16 + quad * 4 + i;
#pragma unroll
                for (int ni = 0; ni < 4; ++ni) {
                    const int n = n0 + wn * 64 + ni * 16 + c;
                    Cout[(size_t)m * E_ + n] = acc[mi][ni][i] + bo[n];
                }
            }
        }
    }
}

// ---------------------------------------------------------------------------
// Flash attention v6: 8-wave (512-thread) blocks, all waves sharing one
// 256-row q block (kb). Each staged K/V tile is consumed by 8 waves.
// 4-buffer depth-2 prefetch, ONE barrier per iteration, counted vmcnt (T3/T4).
// Softmax in-register (T12: v_cvt_pk_bf16_f32 + permlane32_swap), T5 setprio.
// ---------------------------------------------------------------------------
__global__ __launch_bounds__(512, 4) void flash_attn6(
        const short* __restrict__ qg,
        const short* __restrict__ kg,
        const short* __restrict__ vtg,
        const float* __restrict__ biasg,
        short* __restrict__ attn) {
    const int h = blockIdx.x, b = blockIdx.y;
    const int kb = 7 - blockIdx.z;                 // 256-row q block, heavy first
    const int tid  = threadIdx.x;
    const int wave = tid >> 6, lane = tid & 63;
    const int ln = lane & 31, hi = lane >> 5;
    const int q0w = kb * 256 + wave * 32;          // this wave's 32 q rows
    const int mytile = 8 * kb + wave;              // wave's diagonal tile
    const int nt = 8 * kb + 8;

    __shared__ __align__(16) char lds[41984];

    const size_t bh = (size_t)b * H_ + h;
    const short* qbh  = qg  + bh * (size_t)T_ * D_;
    const short* kbh  = kg  + bh * (size_t)T_ * D_;
    const short* vtbh = vtg + bh * (size_t)D_ * T_;
    const float* biasb = biasg + (size_t)b * T_;

    // staging coords: one 16B chunk per thread per tile
    const bool stK = (tid < 256);                  // wave-uniform
    const int t2 = tid & 255;
    const int ks = t2 >> 3, kgs = (t2 & 7) ^ (ks & 7);        // K row / src chunk
    const int vd = t2 >> 2, vgs = ((t2 & 3) - (vd >> 1)) & 3; // V row / src chunk

    // swizzled LDS read offsets (add (tt&3)*8192 at use)
    int kaddr[4];
#pragma unroll
    for (int kc = 0; kc < 4; ++kc)
        kaddr[kc] = ln * 128 + ((((kc << 1) + hi) ^ (ln & 7)) << 4);
    int vaddr[4];                                  // [dh*2 + kc2]
#pragma unroll
    for (int dh = 0; dh < 2; ++dh)
#pragma unroll
        for (int kc2 = 0; kc2 < 2; ++kc2) {
            int d = dh * 32 + ln;
            vaddr[dh * 2 + kc2] =
                4096 + d * 64 + (((((kc2 << 1) + hi) + (d >> 1)) & 3) << 4);
        }

    // Q fragments (B operand of S^T): col=q=ln, k = kc*16 + hi*8 + e
    bf16x8 qf[4];
#pragma unroll
    for (int kc = 0; kc < 4; ++kc)
        qf[kc] = *(const bf16x8*)(qbh + (size_t)(q0w + ln) * D_ + kc * 16 + hi * 8);

    // stage bias[0..2047] -> LDS once (8KB: 512 threads x 16B)
    async_ld16(biasb + ((wave << 6) + lane) * 4, lds + 32768 + wave * 1024);

#define STAGE_T(tt2) do {                                                   \
        const int _s0 = (tt2) << 5;                                         \
        const int _bb = ((tt2) & 3) * 8192;                                 \
        if (stK) async_ld16(kbh + (size_t)(_s0 + ks) * D_ + (kgs << 3),     \
                            lds + _bb + (wave & 3) * 1024);                 \
        else     async_ld16(vtbh + (size_t)vd * T_ + _s0 + (vgs << 3),      \
                            lds + _bb + 4096 + (wave & 3) * 1024);          \
    } while (0)

    STAGE_T(0);
    STAGE_T(1);

    f32x16 O0 = {}, O1 = {};
    float lacc = 0.0f;

    for (int tt = 0; tt < nt; ++tt) {
        if (tt + 2 < nt) STAGE_T(tt + 2);
        const int rem = nt - 1 - tt;               // staged tiles beyond tt
        if (rem >= 2)      asm volatile("s_waitcnt vmcnt(2)" ::: "memory");
        else if (rem == 1) asm volatile("s_waitcnt vmcnt(1)" ::: "memory");
        else               asm volatile("s_waitcnt vmcnt(0)" ::: "memory");
        __builtin_amdgcn_s_barrier();              // tile tt landed everywhere

        if (tt <= mytile) {
            const int s0 = tt << 5;
            const int bb = (tt & 3) * 8192;

            // bias for the 16 s-rows (broadcast ds_read, uniform addr per hi)
            f32x4 b4[4];
#pragma unroll
            for (int g = 0; g < 4; ++g)
                b4[g] = *(const f32x4*)(lds + 32768 + (s0 + g * 8 + hi * 4) * 4);

            // S^T = K . Q^T  (A=K from LDS, B=Q regs); q pre-scaled
            f32x16 S = {};
            __builtin_amdgcn_s_setprio(1);
#pragma unroll
            for (int kc = 0; kc < 4; ++kc) {
                bf16x8 ka = *(const bf16x8*)(lds + bb + kaddr[kc]);
                S = __builtin_amdgcn_mfma_f32_32x32x16_bf16(ka, qf[kc], S, 0, 0, 0);
            }
            __builtin_amdgcn_s_setprio(0);

            float p[16];
#pragma unroll
            for (int r = 0; r < 16; ++r) {
                float bb2 = ((const float*)&b4[r >> 2])[r & 3];
                p[r] = __builtin_amdgcn_exp2f(S[r] + bb2);
            }
            if (tt == mytile) {                    // causal mask on diagonal
#pragma unroll
                for (int r = 0; r < 16; ++r)
                    if (((r & 3) + ((r >> 2) << 3) + (hi << 2)) > ln)
                        p[r] = 0.0f;
            }
            // l partial (tree)
            {
                float t0 = (p[0] + p[1]) + (p[2] + p[3]);
                float t1 = (p[4] + p[5]) + (p[6] + p[7]);
                float t2s = (p[8] + p[9]) + (p[10] + p[11]);
                float t3 = (p[12] + p[13]) + (p[14] + p[15]);
                lacc += (t0 + t1) + (t2s + t3);
            }

            // pack to bf16 (HW cvt_pk) + permlane32_swap -> PV A-frags (T12)
            unsigned int u0, u1, u2, u3, u4, u5, u6, u7;
            asm("v_cvt_pk_bf16_f32 %0, %1, %2" : "=v"(u0) : "v"(p[0]),  "v"(p[1]));
            asm("v_cvt_pk_bf16_f32 %0, %1, %2" : "=v"(u1) : "v"(p[2]),  "v"(p[3]));
            asm("v_cvt_pk_bf16_f32 %0, %1, %2" : "=v"(u2) : "v"(p[4]),  "v"(p[5]));
            asm("v_cvt_pk_bf16_f32 %0, %1, %2" : "=v"(u3) : "v"(p[6]),  "v"(p[7]));
            asm("v_cvt_pk_bf16_f32 %0, %1, %2" : "=v"(u4) : "v"(p[8]),  "v"(p[9]));
            asm("v_cvt_pk_bf16_f32 %0, %1, %2" : "=v"(u5) : "v"(p[10]), "v"(p[11]));
            asm("v_cvt_pk_bf16_f32 %0, %1, %2" : "=v"(u6) : "v"(p[12]), "v"(p[13]));
            asm("v_cvt_pk_bf16_f32 %0, %1, %2" : "=v"(u7) : "v"(p[14]), "v"(p[15]));
            asm("v_permlane32_swap_b32 %0, %1" : "+v"(u0), "+v"(u2));
            asm("v_permlane32_swap_b32 %0, %1" : "+v"(u1), "+v"(u3));
            asm("v_permlane32_swap_b32 %0, %1" : "+v"(u4), "+v"(u6));
            asm("v_permlane32_swap_b32 %0, %1" : "+v"(u5), "+v"(u7));
            union { unsigned int w[4]; bf16x8 v; } pa0, pa1;
            pa0.w[0] = u0; pa0.w[1] = u1; pa0.w[2] = u2; pa0.w[3] = u3;
            pa1.w[0] = u4; pa1.w[1] = u5; pa1.w[2] = u6; pa1.w[3] = u7;

            // O += P . V  (B=V^T slices from LDS)
            bf16x8 v00 = *(const bf16x8*)(lds + bb + vaddr[0]);
            bf16x8 v01 = *(const bf16x8*)(lds + bb + vaddr[1]);
            bf16x8 v10 = *(const bf16x8*)(lds + bb + vaddr[2]);
            bf16x8 v11 = *(const bf16x8*)(lds + bb + vaddr[3]);
            __builtin_amdgcn_s_setprio(1);
            O0 = __builtin_amdgcn_mfma_f32_32x32x16_bf16(pa0.v, v00, O0, 0, 0, 0);
            O0 = __builtin_amdgcn_mfma_f32_32x32x16_bf16(pa1.v, v01, O0, 0, 0, 0);
            O1 = __builtin_amdgcn_mfma_f32_32x32x16_bf16(pa0.v, v10, O1, 0, 0, 0);
            O1 = __builtin_amdgcn_mfma_f32_32x32x16_bf16(pa1.v, v11, O1, 0, 0, 0);
            __builtin_amdgcn_s_setprio(0);
        }
    }
#undef STAGE_T

    // ---- epilogue: combine l across hi-halves, normalize, store -----------
    unsigned int la = __float_as_uint(lacc), lb2 = la;
    asm("v_permlane32_swap_b32 %0, %1" : "+v"(la), "+v"(lb2));
    const float ltot = __uint_as_float(la) + __uint_as_float(lb2);

    float* lsh = (float*)(lds + 40960) + wave * 32;
    if (hi == 0) lsh[ln] = 1.0f / ltot;
    __syncthreads();

    short* ab = attn + (size_t)b * T_ * E_ + h * D_;
#pragma unroll
    for (int r = 0; r < 16; ++r) {
        const int qrow = (r & 3) + ((r >> 2) << 3) + (hi << 2);
        const float iv = lsh[qrow];
        const size_t base = (size_t)(q0w + qrow) * E_;
        ab[base + ln]      = f2bf(O0[r] * iv);
        ab[base + 32 + ln] = f2bf(O1[r] * iv);
    }
}

// ---------------------------------------------------------------------------
extern "C" void kernel_launch(void* const* d_in, const int* in_sizes, int n_in,
                              void* d_out, int out_size, void* d_ws, size_t ws_size,
                              hipStream_t stream) {
    const float* x    = (const float*)d_in[0];
    const float* mask = (const float*)d_in[1];
    const float* Wq   = (const float*)d_in[2];
    const float* Wk   = (const float*)d_in[3];
    const float* Wv   = (const float*)d_in[4];
    const float* Wo   = (const float*)d_in[5];
    const float* bo   = (const float*)d_in[6];
    float* out        = (float*)d_out;

    const size_t S = (size_t)M_ * E_;              // 8.4M elems
    char* ws = (char*)d_ws;
    short* xb   = (short*)ws;                      // bf16 x; reused as attn
    short* qb   = (short*)(ws + S * 2);
    short* kb   = (short*)(ws + S * 4);
    short* vtb  = (short*)(ws + S * 6);            // V stored transposed by MODE0
    short* Wt   = (short*)(ws + S * 8);
    short* Wob  = (short*)(ws + S * 8 + (size_t)3 * 1024 * 1024 * 2);
    float* bias = (float*)(ws + S * 8 + (size_t)4 * 1024 * 1024 * 2);
    short* attnb = xb;

    conv_bf16<<<dim3(M_ * E_ / 1024), 256, 0, stream>>>(x, xb);
    conv_bf16<<<dim3(E_ * E_ / 1024), 256, 0, stream>>>(Wo, Wob);
    wtrans<<<dim3(E_ / 64, H_, 3), 256, 0, stream>>>(Wq, Wk, Wv, Wt);
    bias_prep<<<dim3(B_ * T_ / 256), 256, 0, stream>>>(mask, bias);

    mfma_gemm<0><<<dim3(M_ / 256, 3 * E_ / 128), 512, 0, stream>>>(
        xb, Wt, qb, kb, vtb, nullptr, nullptr);

    flash_attn6<<<dim3(H_, B_, 8), 512, 0, stream>>>(qb, kb, vtb, bias, attnb);

    mfma_gemm<1><<<dim3(M_ / 256, E_ / 128), 512, 0, stream>>>(
        attnb, Wob, nullptr, nullptr, nullptr, out, bo);
}

// Round 6
// 240.207 us; speedup vs baseline: 1.0702x; 1.0491x over previous
//
#include <hip/hip_runtime.h>
#include <hip/hip_bf16.h>

#define B_ 4
#define T_ 2048
#define E_ 1024
#define H_ 16
#define D_ 64
#define M_ (B_*T_)   // 8192 rows

typedef short bf16x8 __attribute__((ext_vector_type(8)));
typedef float f32x4  __attribute__((ext_vector_type(4)));
typedef float f32x16 __attribute__((ext_vector_type(16)));

__device__ __forceinline__ short f2bf(float f) {
    __hip_bfloat16 h = __float2bfloat16(f);
    return *reinterpret_cast<short*>(&h);
}

__device__ __forceinline__ void async_ld16(const void* g, void* l) {
    __builtin_amdgcn_global_load_lds(
        (const __attribute__((address_space(1))) unsigned int*)g,
        (__attribute__((address_space(3))) unsigned int*)l, 16, 0, 0);
}

// ---------------------------------------------------------------------------
// Prep: fp32 -> bf16 elementwise (x and Wo).
// ---------------------------------------------------------------------------
__global__ void conv_bf16(const float* __restrict__ src, short* __restrict__ dst) {
    const int i = blockIdx.x * 256 + threadIdx.x;
    float4 v = ((const float4*)src)[i];
    short4 o = make_short4(f2bf(v.x), f2bf(v.y), f2bf(v.z), f2bf(v.w));
    ((short4*)dst)[i] = o;
}

// ---------------------------------------------------------------------------
// Prep: bias_pre[b][s] = ((1-mask)*(-3.4e38)) * 1.4427 - 6*1.4427
// (exp2-folded additive bias with static max m=6). mask=1 -> -8.6565.
// ---------------------------------------------------------------------------
__global__ void bias_prep(const float* __restrict__ mask, float* __restrict__ bias) {
    const int i = blockIdx.x * 256 + threadIdx.x;
    float bm = (1.0f - mask[i]) * -3.402823466e38f;   // 0 or -3.4e38
    bias[i] = fmaf(bm, 1.4426950f, -8.6561700f);      // -inf ok (exp2 -> 0)
}

// ---------------------------------------------------------------------------
// Prep: Wq/Wk/Wv [H][E][D] fp32 -> Wt [3*1024 n][1024 e] bf16, n = h*64+d.
// ---------------------------------------------------------------------------
__global__ void wtrans(const float* __restrict__ Wq,
                       const float* __restrict__ Wk,
                       const float* __restrict__ Wv,
                       short* __restrict__ Wt) {
    const int which = blockIdx.z;
    const float* __restrict__ W = (which == 0) ? Wq : (which == 1) ? Wk : Wv;
    const int h  = blockIdx.y;
    const int e0 = blockIdx.x * 64;

    __shared__ float tile[64][65];
    const int tid = threadIdx.x;

#pragma unroll
    for (int r = 0; r < 4; ++r) {
        int lin = tid + r * 256;
        int er = lin >> 4, c4 = (lin & 15) * 4;
        float4 v = *(const float4*)(W + ((size_t)h * E_ + e0 + er) * D_ + c4);
        tile[er][c4 + 0] = v.x; tile[er][c4 + 1] = v.y;
        tile[er][c4 + 2] = v.z; tile[er][c4 + 3] = v.w;
    }
    __syncthreads();
#pragma unroll
    for (int r = 0; r < 4; ++r) {
        int lin = tid + r * 256;
        int dr = lin >> 4, j4 = (lin & 15) * 4;
        short4 o = make_short4(f2bf(tile[j4 + 0][dr]), f2bf(tile[j4 + 1][dr]),
                               f2bf(tile[j4 + 2][dr]), f2bf(tile[j4 + 3][dr]));
        *(short4*)(Wt + ((size_t)which * 1024 + h * 64 + dr) * E_ + e0 + j4) = o;
    }
}

// ---------------------------------------------------------------------------
// MFMA GEMM v2 (R5): phase-split counted-vmcnt schedule (T3+T4).
// BM=256, BN=128, BK=64, 8 waves (4M x 2N). 3 K-tile LDS buffers (144 KiB),
// prefetch distance 2 K-tiles, vmcnt(6) once per K-tile (never 0 mid-loop).
// ---------------------------------------------------------------------------
template <int MODE>
__global__ __launch_bounds__(512, 2) void mfma_gemm(
        const short* __restrict__ A,
        const short* __restrict__ Bt,
        short* __restrict__ qo, short* __restrict__ ko, short* __restrict__ vo,
        float* __restrict__ Cout, const float* __restrict__ bo) {
    __shared__ __align__(16) char lds[3 * 49152];   // 144 KiB

    const int tid  = threadIdx.x;
    const int wave = tid >> 6, lane = tid & 63;
    const int c = lane & 15, quad = lane >> 4;
    const int wm = wave >> 1, wn = wave & 1;        // 4M x 2N
    const int m0 = blockIdx.x * 256;
    const int n0 = blockIdx.y * 128;

    // staging coords: unit u (8KB = 64 rows x 128B); thread slot = tid
    const int rr = tid >> 3;                        // row within unit [0,64)
    const int cc = (tid & 7) ^ (rr & 7);            // source 16B chunk

    // fragment read byte-offsets within a buffer (ks toggles via ^64)
    int aoff[4], boff[4];
#pragma unroll
    for (int mi = 0; mi < 4; ++mi) {
        int row = wm * 64 + mi * 16 + c;
        aoff[mi] = row * 128 + ((quad ^ (row & 7)) << 4);
    }
#pragma unroll
    for (int ni = 0; ni < 4; ++ni) {
        int row = wn * 64 + ni * 16 + c;
        boff[ni] = 32768 + row * 128 + ((quad ^ (row & 7)) << 4);
    }

    f32x4 acc[4][4] = {};

#define STGU(bufb, k0v, u) do {                                              \
        const short* _s = ((u) < 4) ? A : Bt;                                \
        const int _b0 = ((u) < 4) ? (m0 + (u) * 64) : (n0 + ((u) - 4) * 64); \
        const int _do = ((u) < 4) ? ((u) * 8192) : (32768 + ((u) - 4) * 8192);\
        async_ld16(_s + (size_t)(_b0 + rr) * 1024 + (k0v) + cc * 8,          \
                   lds + (bufb) + _do + wave * 1024);                        \
    } while (0)

    // prologue: stage K-tiles 0 and 1 (6 loads each)
#pragma unroll
    for (int u = 0; u < 6; ++u) STGU(0, 0, u);
#pragma unroll
    for (int u = 0; u < 6; ++u) STGU(49152, 64, u);
    asm volatile("s_waitcnt vmcnt(6)" ::: "memory");   // K-tile 0 landed
    __builtin_amdgcn_s_barrier();

    int rbase = 0;
#pragma unroll 1
    for (int k = 0; k < 16; ++k) {
        const char* rb = lds + rbase;
        const int wbase = (rbase == 0) ? 98304 : rbase - 49152;
        const int kw = (k + 2) * 64;

        // ---- phase 0 ----
        bf16x8 a_[4][2], b01[2][2];
#pragma unroll
        for (int mi = 0; mi < 4; ++mi)
#pragma unroll
            for (int ks = 0; ks < 2; ++ks)
                a_[mi][ks] = *(const bf16x8*)(rb + (aoff[mi] ^ (ks << 6)));
#pragma unroll
        for (int ni = 0; ni < 2; ++ni)
#pragma unroll
            for (int ks = 0; ks < 2; ++ks)
                b01[ni][ks] = *(const bf16x8*)(rb + (boff[ni] ^ (ks << 6)));
        if (k < 14) {
            STGU(wbase, kw, 0); STGU(wbase, kw, 1);
            STGU(wbase, kw, 2); STGU(wbase, kw, 3);
        }
        __builtin_amdgcn_s_barrier();
        __builtin_amdgcn_s_setprio(1);
#pragma unroll
        for (int mi = 0; mi < 4; ++mi)
#pragma unroll
            for (int ni = 0; ni < 2; ++ni)
#pragma unroll
                for (int ks = 0; ks < 2; ++ks)
                    acc[mi][ni] = __builtin_amdgcn_mfma_f32_16x16x32_bf16(
                        a_[mi][ks], b01[ni][ks], acc[mi][ni], 0, 0, 0);
        __builtin_amdgcn_s_setprio(0);
        __builtin_amdgcn_s_barrier();

        // ---- phase 1 ----
        bf16x8 b23[2][2];
#pragma unroll
        for (int ni = 0; ni < 2; ++ni)
#pragma unroll
            for (int ks = 0; ks < 2; ++ks)
                b23[ni][ks] = *(const bf16x8*)(rb + (boff[2 + ni] ^ (ks << 6)));
        if (k < 14) { STGU(wbase, kw, 4); STGU(wbase, kw, 5); }
        if (k < 14)       asm volatile("s_waitcnt vmcnt(6)" ::: "memory");
        else if (k == 14) asm volatile("s_waitcnt vmcnt(0)" ::: "memory");
        __builtin_amdgcn_s_barrier();
        __builtin_amdgcn_s_setprio(1);
#pragma unroll
        for (int mi = 0; mi < 4; ++mi)
#pragma unroll
            for (int ni = 0; ni < 2; ++ni)
#pragma unroll
                for (int ks = 0; ks < 2; ++ks)
                    acc[mi][2 + ni] = __builtin_amdgcn_mfma_f32_16x16x32_bf16(
                        a_[mi][ks], b23[ni][ks], acc[mi][2 + ni], 0, 0, 0);
        __builtin_amdgcn_s_setprio(0);
        __builtin_amdgcn_s_barrier();

        rbase = (rbase == 98304) ? 0 : rbase + 49152;
    }
#undef STGU

    if (MODE == 0) {
        const int which = n0 >> 10;
        const int nb = n0 & 1023;
        if (which == 2) {
            // V: store transposed [b,h,d,t], vectorized short4 along t
#pragma unroll
            for (int mi = 0; mi < 4; ++mi) {
                const int m = m0 + wm * 64 + mi * 16 + quad * 4;
                const int b = m >> 11, t = m & 2047;
#pragma unroll
                for (int ni = 0; ni < 4; ++ni) {
                    const int n = nb + wn * 64 + ni * 16 + c;
                    const int h = n >> 6, d = n & 63;
                    short4 s4 = make_short4(f2bf(acc[mi][ni][0]), f2bf(acc[mi][ni][1]),
                                            f2bf(acc[mi][ni][2]), f2bf(acc[mi][ni][3]));
                    *(short4*)(vo + (((size_t)b * H_ + h) * D_ + d) * T_ + t) = s4;
                }
            }
        } else {
            short* __restrict__ outp = (which == 0) ? qo : ko;
            // q pre-scaled by 1/sqrt(D)*log2(e) so flash uses exp2(S + bias)
            const float sc = (which == 0) ? 0.18033688f : 1.0f;
#pragma unroll
            for (int mi = 0; mi < 4; ++mi) {
#pragma unroll
                for (int i = 0; i < 4; ++i) {
                    const int m = m0 + wm * 64 + mi * 16 + quad * 4 + i;
                    const int b = m >> 11, t = m & 2047;
#pragma unroll
                    for (int ni = 0; ni < 4; ++ni) {
                        const int n = nb + wn * 64 + ni * 16 + c;
                        const int h = n >> 6, d = n & 63;
                        outp[(((size_t)b * H_ + h) * T_ + t) * D_ + d] =
                            f2bf(acc[mi][ni][i] * sc);
                    }
                }
            }
        }
    } else {
#pragma unroll
        for (int mi = 0; mi < 4; ++mi) {
#pragma unroll
            for (int i = 0; i < 4; ++i) {
                const int m = m0 + wm * 64 + mi * 16 + quad * 4 + i;
#pragma unroll
                for (int ni = 0; ni < 4; ++ni) {
                    const int n = n0 + wn * 64 + ni * 16 + c;
                    Cout[(size_t)m * E_ + n] = acc[mi][ni][i] + bo[n];
                }
            }
        }
    }
}

// ---------------------------------------------------------------------------
// Flash attention v7 (R6): 4-wave (256-thread) blocks on 128-row q blocks.
// 1024 blocks (kb=0..15, heavy-first), LDS trimmed to 40960 B so FOUR blocks
// co-reside per CU (16 waves/CU = 4 waves/SIMD) — the occupancy lever.
// Same verified per-tile compute (swapped 32x32 MFMA, in-register softmax
// T12, both-sides K/V swizzles), same 4-buffer depth-2 counted-vmcnt
// pipeline; staging is now 2 chunks/thread (K+V), so vmcnt counts double.
//
// LDS map: [0,32768) 4 x {4KB K + 4KB V}; [32768,40960) bias;
//          l-scratch overlays buffer 0 after the loop (behind a barrier).
// ---------------------------------------------------------------------------
__global__ __launch_bounds__(256, 4) void flash_attn7(
        const short* __restrict__ qg,
        const short* __restrict__ kg,
        const short* __restrict__ vtg,
        const float* __restrict__ biasg,
        short* __restrict__ attn) {
    const int h = blockIdx.x, b = blockIdx.y;
    const int kb = 15 - blockIdx.z;                // 128-row q block, heavy first
    const int tid  = threadIdx.x;
    const int wave = tid >> 6, lane = tid & 63;
    const int ln = lane & 31, hi = lane >> 5;
    const int q0w = kb * 128 + wave * 32;          // this wave's 32 q rows
    const int mytile = 4 * kb + wave;              // wave's diagonal tile
    const int nt = 4 * kb + 4;

    __shared__ __align__(16) char lds[40960];

    const size_t bh = (size_t)b * H_ + h;
    const short* qbh  = qg  + bh * (size_t)T_ * D_;
    const short* kbh  = kg  + bh * (size_t)T_ * D_;
    const short* vtbh = vtg + bh * (size_t)D_ * T_;
    const float* biasb = biasg + (size_t)b * T_;

    // staging coords: each thread stages ONE K chunk and ONE V chunk per tile
    const int ks = tid >> 3, kgs = (tid & 7) ^ (ks & 7);        // K row / src chunk
    const int vd = tid >> 2, vgs = ((tid & 3) - (vd >> 1)) & 3; // V row / src chunk

    // swizzled LDS read offsets (add (tt&3)*8192 at use)
    int kaddr[4];
#pragma unroll
    for (int kc = 0; kc < 4; ++kc)
        kaddr[kc] = ln * 128 + ((((kc << 1) + hi) ^ (ln & 7)) << 4);
    int vaddr[4];                                  // [dh*2 + kc2]
#pragma unroll
    for (int dh = 0; dh < 2; ++dh)
#pragma unroll
        for (int kc2 = 0; kc2 < 2; ++kc2) {
            int d = dh * 32 + ln;
            vaddr[dh * 2 + kc2] =
                4096 + d * 64 + (((((kc2 << 1) + hi) + (d >> 1)) & 3) << 4);
        }

    // Q fragments (B operand of S^T): col=q=ln, k = kc*16 + hi*8 + e
    bf16x8 qf[4];
#pragma unroll
    for (int kc = 0; kc < 4; ++kc)
        qf[kc] = *(const bf16x8*)(qbh + (size_t)(q0w + ln) * D_ + kc * 16 + hi * 8);

    // stage bias[0..2047] -> LDS once (8KB: 256 threads x 16B x 2 rounds)
#pragma unroll
    for (int r = 0; r < 2; ++r)
        async_ld16(biasb + r * 1024 + tid * 4,
                   lds + 32768 + r * 4096 + wave * 1024);

#define STAGE_T(tt2) do {                                                   \
        const int _s0 = (tt2) << 5;                                         \
        const int _bb = ((tt2) & 3) * 8192;                                 \
        async_ld16(kbh + (size_t)(_s0 + ks) * D_ + (kgs << 3),              \
                   lds + _bb + wave * 1024);                                \
        async_ld16(vtbh + (size_t)vd * T_ + _s0 + (vgs << 3),               \
                   lds + _bb + 4096 + wave * 1024);                         \
    } while (0)

    STAGE_T(0);
    STAGE_T(1);

    f32x16 O0 = {}, O1 = {};
    float lacc = 0.0f;

    for (int tt = 0; tt < nt; ++tt) {
        if (tt + 2 < nt) STAGE_T(tt + 2);
        const int rem = nt - 1 - tt;               // staged tiles beyond tt
        if (rem >= 2)      asm volatile("s_waitcnt vmcnt(4)" ::: "memory");
        else if (rem == 1) asm volatile("s_waitcnt vmcnt(2)" ::: "memory");
        else               asm volatile("s_waitcnt vmcnt(0)" ::: "memory");
        __builtin_amdgcn_s_barrier();              // tile tt landed everywhere

        if (tt <= mytile) {
            const int s0 = tt << 5;
            const int bb = (tt & 3) * 8192;

            // bias for the 16 s-rows (broadcast ds_read, uniform addr per hi)
            f32x4 b4[4];
#pragma unroll
            for (int g = 0; g < 4; ++g)
                b4[g] = *(const f32x4*)(lds + 32768 + (s0 + g * 8 + hi * 4) * 4);

            // S^T = K . Q^T  (A=K from LDS, B=Q regs); q pre-scaled
            f32x16 S = {};
            __builtin_amdgcn_s_setprio(1);
#pragma unroll
            for (int kc = 0; kc < 4; ++kc) {
                bf16x8 ka = *(const bf16x8*)(lds + bb + kaddr[kc]);
                S = __builtin_amdgcn_mfma_f32_32x32x16_bf16(ka, qf[kc], S, 0, 0, 0);
            }
            __builtin_amdgcn_s_setprio(0);

            float p[16];
#pragma unroll
            for (int r = 0; r < 16; ++r) {
                float bb2 = ((const float*)&b4[r >> 2])[r & 3];
                p[r] = __builtin_amdgcn_exp2f(S[r] + bb2);
            }
            if (tt == mytile) {                    // causal mask on diagonal
#pragma unroll
                for (int r = 0; r < 16; ++r)
                    if (((r & 3) + ((r >> 2) << 3) + (hi << 2)) > ln)
                        p[r] = 0.0f;
            }
            // l partial (tree)
            {
                float t0 = (p[0] + p[1]) + (p[2] + p[3]);
                float t1 = (p[4] + p[5]) + (p[6] + p[7]);
                float t2s = (p[8] + p[9]) + (p[10] + p[11]);
                float t3 = (p[12] + p[13]) + (p[14] + p[15]);
                lacc += (t0 + t1) + (t2s + t3);
            }

            // pack to bf16 (HW cvt_pk) + permlane32_swap -> PV A-frags (T12)
            unsigned int u0, u1, u2, u3, u4, u5, u6, u7;
            asm("v_cvt_pk_bf16_f32 %0, %1, %2" : "=v"(u0) : "v"(p[0]),  "v"(p[1]));
            asm("v_cvt_pk_bf16_f32 %0, %1, %2" : "=v"(u1) : "v"(p[2]),  "v"(p[3]));
            asm("v_cvt_pk_bf16_f32 %0, %1, %2" : "=v"(u2) : "v"(p[4]),  "v"(p[5]));
            asm("v_cvt_pk_bf16_f32 %0, %1, %2" : "=v"(u3) : "v"(p[6]),  "v"(p[7]));
            asm("v_cvt_pk_bf16_f32 %0, %1, %2" : "=v"(u4) : "v"(p[8]),  "v"(p[9]));
            asm("v_cvt_pk_bf16_f32 %0, %1, %2" : "=v"(u5) : "v"(p[10]), "v"(p[11]));
            asm("v_cvt_pk_bf16_f32 %0, %1, %2" : "=v"(u6) : "v"(p[12]), "v"(p[13]));
            asm("v_cvt_pk_bf16_f32 %0, %1, %2" : "=v"(u7) : "v"(p[14]), "v"(p[15]));
            asm("v_permlane32_swap_b32 %0, %1" : "+v"(u0), "+v"(u2));
            asm("v_permlane32_swap_b32 %0, %1" : "+v"(u1), "+v"(u3));
            asm("v_permlane32_swap_b32 %0, %1" : "+v"(u4), "+v"(u6));
            asm("v_permlane32_swap_b32 %0, %1" : "+v"(u5), "+v"(u7));
            union { unsigned int w[4]; bf16x8 v; } pa0, pa1;
            pa0.w[0] = u0; pa0.w[1] = u1; pa0.w[2] = u2; pa0.w[3] = u3;
            pa1.w[0] = u4; pa1.w[1] = u5; pa1.w[2] = u6; pa1.w[3] = u7;

            // O += P . V  (B=V^T slices from LDS)
            bf16x8 v00 = *(const bf16x8*)(lds + bb + vaddr[0]);
            bf16x8 v01 = *(const bf16x8*)(lds + bb + vaddr[1]);
            bf16x8 v10 = *(const bf16x8*)(lds + bb + vaddr[2]);
            bf16x8 v11 = *(const bf16x8*)(lds + bb + vaddr[3]);
            __builtin_amdgcn_s_setprio(1);
            O0 = __builtin_amdgcn_mfma_f32_32x32x16_bf16(pa0.v, v00, O0, 0, 0, 0);
            O0 = __builtin_amdgcn_mfma_f32_32x32x16_bf16(pa1.v, v01, O0, 0, 0, 0);
            O1 = __builtin_amdgcn_mfma_f32_32x32x16_bf16(pa0.v, v10, O1, 0, 0, 0);
            O1 = __builtin_amdgcn_mfma_f32_32x32x16_bf16(pa1.v, v11, O1, 0, 0, 0);
            __builtin_amdgcn_s_setprio(0);
        }
    }
#undef STAGE_T

    // ---- epilogue: combine l across hi-halves, normalize, store -----------
    unsigned int la = __float_as_uint(lacc), lb2 = la;
    asm("v_permlane32_swap_b32 %0, %1" : "+v"(la), "+v"(lb2));
    const float ltot = __uint_as_float(la) + __uint_as_float(lb2);

    __syncthreads();                               // all buf reads done
    float* lsh = (float*)lds + wave * 32;          // overlay buffer 0
    if (hi == 0) lsh[ln] = 1.0f / ltot;
    __syncthreads();

    short* ab = attn + (size_t)b * T_ * E_ + h * D_;
#pragma unroll
    for (int r = 0; r < 16; ++r) {
        const int qrow = (r & 3) + ((r >> 2) << 3) + (hi << 2);
        const float iv = lsh[qrow];
        const size_t base = (size_t)(q0w + qrow) * E_;
        ab[base + ln]      = f2bf(O0[r] * iv);
        ab[base + 32 + ln] = f2bf(O1[r] * iv);
    }
}

// ---------------------------------------------------------------------------
extern "C" void kernel_launch(void* const* d_in, const int* in_sizes, int n_in,
                              void* d_out, int out_size, void* d_ws, size_t ws_size,
                              hipStream_t stream) {
    const float* x    = (const float*)d_in[0];
    const float* mask = (const float*)d_in[1];
    const float* Wq   = (const float*)d_in[2];
    const float* Wk   = (const float*)d_in[3];
    const float* Wv   = (const float*)d_in[4];
    const float* Wo   = (const float*)d_in[5];
    const float* bo   = (const float*)d_in[6];
    float* out        = (float*)d_out;

    const size_t S = (size_t)M_ * E_;              // 8.4M elems
    char* ws = (char*)d_ws;
    short* xb   = (short*)ws;                      // bf16 x; reused as attn
    short* qb   = (short*)(ws + S * 2);
    short* kb   = (short*)(ws + S * 4);
    short* vtb  = (short*)(ws + S * 6);            // V stored transposed by MODE0
    short* Wt   = (short*)(ws + S * 8);
    short* Wob  = (short*)(ws + S * 8 + (size_t)3 * 1024 * 1024 * 2);
    float* bias = (float*)(ws + S * 8 + (size_t)4 * 1024 * 1024 * 2);
    short* attnb = xb;

    conv_bf16<<<dim3(M_ * E_ / 1024), 256, 0, stream>>>(x, xb);
    conv_bf16<<<dim3(E_ * E_ / 1024), 256, 0, stream>>>(Wo, Wob);
    wtrans<<<dim3(E_ / 64, H_, 3), 256, 0, stream>>>(Wq, Wk, Wv, Wt);
    bias_prep<<<dim3(B_ * T_ / 256), 256, 0, stream>>>(mask, bias);

    mfma_gemm<0><<<dim3(M_ / 256, 3 * E_ / 128), 512, 0, stream>>>(
        xb, Wt, qb, kb, vtb, nullptr, nullptr);

    flash_attn7<<<dim3(H_, B_, 16), 256, 0, stream>>>(qb, kb, vtb, bias, attnb);

    mfma_gemm<1><<<dim3(M_ / 256, E_ / 128), 512, 0, stream>>>(
        attnb, Wob, nullptr, nullptr, nullptr, out, bo);
}

// Round 7
// 237.564 us; speedup vs baseline: 1.0821x; 1.0111x over previous
//
#include <hip/hip_runtime.h>
#include <hip/hip_bf16.h>

#define B_ 4
#define T_ 2048
#define E_ 1024
#define H_ 16
#define D_ 64
#define M_ (B_*T_)   // 8192 rows

typedef short bf16x8 __attribute__((ext_vector_type(8)));
typedef float f32x4  __attribute__((ext_vector_type(4)));
typedef float f32x16 __attribute__((ext_vector_type(16)));

__device__ __forceinline__ short f2bf(float f) {
    __hip_bfloat16 h = __float2bfloat16(f);
    return *reinterpret_cast<short*>(&h);
}

__device__ __forceinline__ void async_ld16(const void* g, void* l) {
    __builtin_amdgcn_global_load_lds(
        (const __attribute__((address_space(1))) unsigned int*)g,
        (__attribute__((address_space(3))) unsigned int*)l, 16, 0, 0);
}

// ---------------------------------------------------------------------------
// Prep: fp32 -> bf16 elementwise (x and Wo).
// ---------------------------------------------------------------------------
__global__ void conv_bf16(const float* __restrict__ src, short* __restrict__ dst) {
    const int i = blockIdx.x * 256 + threadIdx.x;
    float4 v = ((const float4*)src)[i];
    short4 o = make_short4(f2bf(v.x), f2bf(v.y), f2bf(v.z), f2bf(v.w));
    ((short4*)dst)[i] = o;
}

// ---------------------------------------------------------------------------
// Prep: bias_pre[b][s] = ((1-mask)*(-3.4e38)) * 1.4427 - 6*1.4427
// (exp2-folded additive bias with static max m=6). mask=1 -> -8.6565.
// ---------------------------------------------------------------------------
__global__ void bias_prep(const float* __restrict__ mask, float* __restrict__ bias) {
    const int i = blockIdx.x * 256 + threadIdx.x;
    float bm = (1.0f - mask[i]) * -3.402823466e38f;   // 0 or -3.4e38
    bias[i] = fmaf(bm, 1.4426950f, -8.6561700f);      // -inf ok (exp2 -> 0)
}

// ---------------------------------------------------------------------------
// Prep: Wq/Wk/Wv [H][E][D] fp32 -> Wt [3*1024 n][1024 e] bf16, n = h*64+d.
// ---------------------------------------------------------------------------
__global__ void wtrans(const float* __restrict__ Wq,
                       const float* __restrict__ Wk,
                       const float* __restrict__ Wv,
                       short* __restrict__ Wt) {
    const int which = blockIdx.z;
    const float* __restrict__ W = (which == 0) ? Wq : (which == 1) ? Wk : Wv;
    const int h  = blockIdx.y;
    const int e0 = blockIdx.x * 64;

    __shared__ float tile[64][65];
    const int tid = threadIdx.x;

#pragma unroll
    for (int r = 0; r < 4; ++r) {
        int lin = tid + r * 256;
        int er = lin >> 4, c4 = (lin & 15) * 4;
        float4 v = *(const float4*)(W + ((size_t)h * E_ + e0 + er) * D_ + c4);
        tile[er][c4 + 0] = v.x; tile[er][c4 + 1] = v.y;
        tile[er][c4 + 2] = v.z; tile[er][c4 + 3] = v.w;
    }
    __syncthreads();
#pragma unroll
    for (int r = 0; r < 4; ++r) {
        int lin = tid + r * 256;
        int dr = lin >> 4, j4 = (lin & 15) * 4;
        short4 o = make_short4(f2bf(tile[j4 + 0][dr]), f2bf(tile[j4 + 1][dr]),
                               f2bf(tile[j4 + 2][dr]), f2bf(tile[j4 + 3][dr]));
        *(short4*)(Wt + ((size_t)which * 1024 + h * 64 + dr) * E_ + e0 + j4) = o;
    }
}

// ---------------------------------------------------------------------------
// MFMA GEMM v3 (R7): single-barrier counted-vmcnt K-loop.
// BM=256, BN=128, BK=64, 8 waves (4M x 2N). 3 K-tile LDS buffers (144 KiB),
// prefetch distance 2 K-tiles. Per K-tile k, ONE phase:
//   stage(k+2) -> 16 ds_read (compiler-interleaved via lgkmcnt with)
//   -> 32 MFMA (setprio) -> vmcnt(6) -> barrier.
// Race: stage(k+2) overwrites buf[(k-1)%3]; its readers (iter k-1) consumed
// every ds_read before the end-of-(k-1) barrier (each read feeds an MFMA
// guarded by lgkmcnt). Data-ready: vmcnt(6) at end of iter k-1 leaves only
// stage(k+1)'s 6 loads in flight => tile k landed block-wide. Tail: k=14
// drains vmcnt(0) (covers tile 15); k=15 stages nothing.
//
// Buffer layout (48KB each): A[256][64] bf16 at +0, B[128][64] at +32768.
// 16B-chunk XOR swizzle g = src_chunk ^ (row&7) (involution, both sides).
//
// MODE 0: C -> q/k bf16 [B,H,T,D] scatter; q PRE-SCALED by 1/sqrt(D)*log2e.
//         V directly TRANSPOSED [B,H,D,T].  Grid (32, 24) = 3 exact rounds.
// MODE 1: C -> fp32 [M][E] + bias.          Grid (32, 8)  = 1 exact round.
// ---------------------------------------------------------------------------
template <int MODE>
__global__ __launch_bounds__(512, 2) void mfma_gemm(
        const short* __restrict__ A,
        const short* __restrict__ Bt,
        short* __restrict__ qo, short* __restrict__ ko, short* __restrict__ vo,
        float* __restrict__ Cout, const float* __restrict__ bo) {
    __shared__ __align__(16) char lds[3 * 49152];   // 144 KiB

    const int tid  = threadIdx.x;
    const int wave = tid >> 6, lane = tid & 63;
    const int c = lane & 15, quad = lane >> 4;
    const int wm = wave >> 1, wn = wave & 1;        // 4M x 2N
    const int m0 = blockIdx.x * 256;
    const int n0 = blockIdx.y * 128;

    // staging coords: unit u (8KB = 64 rows x 128B); thread slot = tid
    const int rr = tid >> 3;                        // row within unit [0,64)
    const int cc = (tid & 7) ^ (rr & 7);            // source 16B chunk

    // fragment read byte-offsets within a buffer (ks toggles via ^64)
    int aoff[4], boff[4];
#pragma unroll
    for (int mi = 0; mi < 4; ++mi) {
        int row = wm * 64 + mi * 16 + c;
        aoff[mi] = row * 128 + ((quad ^ (row & 7)) << 4);
    }
#pragma unroll
    for (int ni = 0; ni < 4; ++ni) {
        int row = wn * 64 + ni * 16 + c;
        boff[ni] = 32768 + row * 128 + ((quad ^ (row & 7)) << 4);
    }

    f32x4 acc[4][4] = {};

#define STGU(bufb, k0v, u) do {                                              \
        const short* _s = ((u) < 4) ? A : Bt;                                \
        const int _b0 = ((u) < 4) ? (m0 + (u) * 64) : (n0 + ((u) - 4) * 64); \
        const int _do = ((u) < 4) ? ((u) * 8192) : (32768 + ((u) - 4) * 8192);\
        async_ld16(_s + (size_t)(_b0 + rr) * 1024 + (k0v) + cc * 8,          \
                   lds + (bufb) + _do + wave * 1024);                        \
    } while (0)

    // prologue: stage K-tiles 0 and 1 (6 loads each)
#pragma unroll
    for (int u = 0; u < 6; ++u) STGU(0, 0, u);
#pragma unroll
    for (int u = 0; u < 6; ++u) STGU(49152, 64, u);
    asm volatile("s_waitcnt vmcnt(6)" ::: "memory");   // K-tile 0 landed
    __builtin_amdgcn_s_barrier();

    int rbase = 0;
#pragma unroll 1
    for (int k = 0; k < 16; ++k) {
        const char* rb = lds + rbase;
        const int wbase = (rbase == 0) ? 98304 : rbase - 49152;
        const int kw = (k + 2) * 64;

        // prefetch K-tile k+2 (issue early; lands under 2 K-tiles of compute)
        if (k < 14) {
            STGU(wbase, kw, 0); STGU(wbase, kw, 1);
            STGU(wbase, kw, 2); STGU(wbase, kw, 3);
            STGU(wbase, kw, 4); STGU(wbase, kw, 5);
        }

        // fragments for the whole K-tile (compiler interleaves with MFMA
        // via counted lgkmcnt)
        bf16x8 a_[4][2], b_[4][2];
#pragma unroll
        for (int mi = 0; mi < 4; ++mi)
#pragma unroll
            for (int ks = 0; ks < 2; ++ks)
                a_[mi][ks] = *(const bf16x8*)(rb + (aoff[mi] ^ (ks << 6)));
#pragma unroll
        for (int ni = 0; ni < 4; ++ni)
#pragma unroll
            for (int ks = 0; ks < 2; ++ks)
                b_[ni][ks] = *(const bf16x8*)(rb + (boff[ni] ^ (ks << 6)));

        __builtin_amdgcn_s_setprio(1);
#pragma unroll
        for (int mi = 0; mi < 4; ++mi)
#pragma unroll
            for (int ni = 0; ni < 4; ++ni)
#pragma unroll
                for (int ks = 0; ks < 2; ++ks)
                    acc[mi][ni] = __builtin_amdgcn_mfma_f32_16x16x32_bf16(
                        a_[mi][ks], b_[ni][ks], acc[mi][ni], 0, 0, 0);
        __builtin_amdgcn_s_setprio(0);

        if (k < 14)       asm volatile("s_waitcnt vmcnt(6)" ::: "memory");
        else if (k == 14) asm volatile("s_waitcnt vmcnt(0)" ::: "memory");
        if (k < 15) __builtin_amdgcn_s_barrier();

        rbase = (rbase == 98304) ? 0 : rbase + 49152;
    }
#undef STGU

    if (MODE == 0) {
        const int which = n0 >> 10;
        const int nb = n0 & 1023;
        if (which == 2) {
            // V: store transposed [b,h,d,t], vectorized short4 along t
#pragma unroll
            for (int mi = 0; mi < 4; ++mi) {
                const int m = m0 + wm * 64 + mi * 16 + quad * 4;
                const int b = m >> 11, t = m & 2047;
#pragma unroll
                for (int ni = 0; ni < 4; ++ni) {
                    const int n = nb + wn * 64 + ni * 16 + c;
                    const int h = n >> 6, d = n & 63;
                    short4 s4 = make_short4(f2bf(acc[mi][ni][0]), f2bf(acc[mi][ni][1]),
                                            f2bf(acc[mi][ni][2]), f2bf(acc[mi][ni][3]));
                    *(short4*)(vo + (((size_t)b * H_ + h) * D_ + d) * T_ + t) = s4;
                }
            }
        } else {
            short* __restrict__ outp = (which == 0) ? qo : ko;
            // q pre-scaled by 1/sqrt(D)*log2(e) so flash uses exp2(S + bias)
            const float sc = (which == 0) ? 0.18033688f : 1.0f;
#pragma unroll
            for (int mi = 0; mi < 4; ++mi) {
#pragma unroll
                for (int i = 0; i < 4; ++i) {
                    const int m = m0 + wm * 64 + mi * 16 + quad * 4 + i;
                    const int b = m >> 11, t = m & 2047;
#pragma unroll
                    for (int ni = 0; ni < 4; ++ni) {
                        const int n = nb + wn * 64 + ni * 16 + c;
                        const int h = n >> 6, d = n & 63;
                        outp[(((size_t)b * H_ + h) * T_ + t) * D_ + d] =
                            f2bf(acc[mi][ni][i] * sc);
                    }
                }
            }
        }
    } else {
#pragma unroll
        for (int mi = 0; mi < 4; ++mi) {
#pragma unroll
            for (int i = 0; i < 4; ++i) {
                const int m = m0 + wm * 64 + mi * 16 + quad * 4 + i;
#pragma unroll
                for (int ni = 0; ni < 4; ++ni) {
                    const int n = n0 + wn * 64 + ni * 16 + c;
                    Cout[(size_t)m * E_ + n] = acc[mi][ni][i] + bo[n];
                }
            }
        }
    }
}

// ---------------------------------------------------------------------------
// Flash attention v7 (R6): 4-wave (256-thread) blocks on 128-row q blocks.
// 1024 blocks (kb=0..15, heavy-first), LDS 40960 B -> 4 blocks/CU
// (16 waves/CU). Swapped 32x32 MFMA, in-register softmax (T12), both-sides
// K/V swizzles, 4-buffer depth-2 counted-vmcnt pipeline, T5 setprio.
// ---------------------------------------------------------------------------
__global__ __launch_bounds__(256, 4) void flash_attn7(
        const short* __restrict__ qg,
        const short* __restrict__ kg,
        const short* __restrict__ vtg,
        const float* __restrict__ biasg,
        short* __restrict__ attn) {
    const int h = blockIdx.x, b = blockIdx.y;
    const int kb = 15 - blockIdx.z;                // 128-row q block, heavy first
    const int tid  = threadIdx.x;
    const int wave = tid >> 6, lane = tid & 63;
    const int ln = lane & 31, hi = lane >> 5;
    const int q0w = kb * 128 + wave * 32;          // this wave's 32 q rows
    const int mytile = 4 * kb + wave;              // wave's diagonal tile
    const int nt = 4 * kb + 4;

    __shared__ __align__(16) char lds[40960];

    const size_t bh = (size_t)b * H_ + h;
    const short* qbh  = qg  + bh * (size_t)T_ * D_;
    const short* kbh  = kg  + bh * (size_t)T_ * D_;
    const short* vtbh = vtg + bh * (size_t)D_ * T_;
    const float* biasb = biasg + (size_t)b * T_;

    // staging coords: each thread stages ONE K chunk and ONE V chunk per tile
    const int ks = tid >> 3, kgs = (tid & 7) ^ (ks & 7);        // K row / src chunk
    const int vd = tid >> 2, vgs = ((tid & 3) - (vd >> 1)) & 3; // V row / src chunk

    // swizzled LDS read offsets (add (tt&3)*8192 at use)
    int kaddr[4];
#pragma unroll
    for (int kc = 0; kc < 4; ++kc)
        kaddr[kc] = ln * 128 + ((((kc << 1) + hi) ^ (ln & 7)) << 4);
    int vaddr[4];                                  // [dh*2 + kc2]
#pragma unroll
    for (int dh = 0; dh < 2; ++dh)
#pragma unroll
        for (int kc2 = 0; kc2 < 2; ++kc2) {
            int d = dh * 32 + ln;
            vaddr[dh * 2 + kc2] =
                4096 + d * 64 + (((((kc2 << 1) + hi) + (d >> 1)) & 3) << 4);
        }

    // Q fragments (B operand of S^T): col=q=ln, k = kc*16 + hi*8 + e
    bf16x8 qf[4];
#pragma unroll
    for (int kc = 0; kc < 4; ++kc)
        qf[kc] = *(const bf16x8*)(qbh + (size_t)(q0w + ln) * D_ + kc * 16 + hi * 8);

    // stage bias[0..2047] -> LDS once (8KB: 256 threads x 16B x 2 rounds)
#pragma unroll
    for (int r = 0; r < 2; ++r)
        async_ld16(biasb + r * 1024 + tid * 4,
                   lds + 32768 + r * 4096 + wave * 1024);

#define STAGE_T(tt2) do {                                                   \
        const int _s0 = (tt2) << 5;                                         \
        const int _bb = ((tt2) & 3) * 8192;                                 \
        async_ld16(kbh + (size_t)(_s0 + ks) * D_ + (kgs << 3),              \
                   lds + _bb + wave * 1024);                                \
        async_ld16(vtbh + (size_t)vd * T_ + _s0 + (vgs << 3),               \
                   lds + _bb + 4096 + wave * 1024);                         \
    } while (0)

    STAGE_T(0);
    STAGE_T(1);

    f32x16 O0 = {}, O1 = {};
    float lacc = 0.0f;

    for (int tt = 0; tt < nt; ++tt) {
        if (tt + 2 < nt) STAGE_T(tt + 2);
        const int rem = nt - 1 - tt;               // staged tiles beyond tt
        if (rem >= 2)      asm volatile("s_waitcnt vmcnt(4)" ::: "memory");
        else if (rem == 1) asm volatile("s_waitcnt vmcnt(2)" ::: "memory");
        else               asm volatile("s_waitcnt vmcnt(0)" ::: "memory");
        __builtin_amdgcn_s_barrier();              // tile tt landed everywhere

        if (tt <= mytile) {
            const int s0 = tt << 5;
            const int bb = (tt & 3) * 8192;

            // bias for the 16 s-rows (broadcast ds_read, uniform addr per hi)
            f32x4 b4[4];
#pragma unroll
            for (int g = 0; g < 4; ++g)
                b4[g] = *(const f32x4*)(lds + 32768 + (s0 + g * 8 + hi * 4) * 4);

            // S^T = K . Q^T  (A=K from LDS, B=Q regs); q pre-scaled
            f32x16 S = {};
            __builtin_amdgcn_s_setprio(1);
#pragma unroll
            for (int kc = 0; kc < 4; ++kc) {
                bf16x8 ka = *(const bf16x8*)(lds + bb + kaddr[kc]);
                S = __builtin_amdgcn_mfma_f32_32x32x16_bf16(ka, qf[kc], S, 0, 0, 0);
            }
            __builtin_amdgcn_s_setprio(0);

            float p[16];
#pragma unroll
            for (int r = 0; r < 16; ++r) {
                float bb2 = ((const float*)&b4[r >> 2])[r & 3];
                p[r] = __builtin_amdgcn_exp2f(S[r] + bb2);
            }
            if (tt == mytile) {                    // causal mask on diagonal
#pragma unroll
                for (int r = 0; r < 16; ++r)
                    if (((r & 3) + ((r >> 2) << 3) + (hi << 2)) > ln)
                        p[r] = 0.0f;
            }
            // l partial (tree)
            {
                float t0 = (p[0] + p[1]) + (p[2] + p[3]);
                float t1 = (p[4] + p[5]) + (p[6] + p[7]);
                float t2s = (p[8] + p[9]) + (p[10] + p[11]);
                float t3 = (p[12] + p[13]) + (p[14] + p[15]);
                lacc += (t0 + t1) + (t2s + t3);
            }

            // pack to bf16 (HW cvt_pk) + permlane32_swap -> PV A-frags (T12)
            unsigned int u0, u1, u2, u3, u4, u5, u6, u7;
            asm("v_cvt_pk_bf16_f32 %0, %1, %2" : "=v"(u0) : "v"(p[0]),  "v"(p[1]));
            asm("v_cvt_pk_bf16_f32 %0, %1, %2" : "=v"(u1) : "v"(p[2]),  "v"(p[3]));
            asm("v_cvt_pk_bf16_f32 %0, %1, %2" : "=v"(u2) : "v"(p[4]),  "v"(p[5]));
            asm("v_cvt_pk_bf16_f32 %0, %1, %2" : "=v"(u3) : "v"(p[6]),  "v"(p[7]));
            asm("v_cvt_pk_bf16_f32 %0, %1, %2" : "=v"(u4) : "v"(p[8]),  "v"(p[9]));
            asm("v_cvt_pk_bf16_f32 %0, %1, %2" : "=v"(u5) : "v"(p[10]), "v"(p[11]));
            asm("v_cvt_pk_bf16_f32 %0, %1, %2" : "=v"(u6) : "v"(p[12]), "v"(p[13]));
            asm("v_cvt_pk_bf16_f32 %0, %1, %2" : "=v"(u7) : "v"(p[14]), "v"(p[15]));
            asm("v_permlane32_swap_b32 %0, %1" : "+v"(u0), "+v"(u2));
            asm("v_permlane32_swap_b32 %0, %1" : "+v"(u1), "+v"(u3));
            asm("v_permlane32_swap_b32 %0, %1" : "+v"(u4), "+v"(u6));
            asm("v_permlane32_swap_b32 %0, %1" : "+v"(u5), "+v"(u7));
            union { unsigned int w[4]; bf16x8 v; } pa0, pa1;
            pa0.w[0] = u0; pa0.w[1] = u1; pa0.w[2] = u2; pa0.w[3] = u3;
            pa1.w[0] = u4; pa1.w[1] = u5; pa1.w[2] = u6; pa1.w[3] = u7;

            // O += P . V  (B=V^T slices from LDS)
            bf16x8 v00 = *(const bf16x8*)(lds + bb + vaddr[0]);
            bf16x8 v01 = *(const bf16x8*)(lds + bb + vaddr[1]);
            bf16x8 v10 = *(const bf16x8*)(lds + bb + vaddr[2]);
            bf16x8 v11 = *(const bf16x8*)(lds + bb + vaddr[3]);
            __builtin_amdgcn_s_setprio(1);
            O0 = __builtin_amdgcn_mfma_f32_32x32x16_bf16(pa0.v, v00, O0, 0, 0, 0);
            O0 = __builtin_amdgcn_mfma_f32_32x32x16_bf16(pa1.v, v01, O0, 0, 0, 0);
            O1 = __builtin_amdgcn_mfma_f32_32x32x16_bf16(pa0.v, v10, O1, 0, 0, 0);
            O1 = __builtin_amdgcn_mfma_f32_32x32x16_bf16(pa1.v, v11, O1, 0, 0, 0);
            __builtin_amdgcn_s_setprio(0);
        }
    }
#undef STAGE_T

    // ---- epilogue: combine l across hi-halves, normalize, store -----------
    unsigned int la = __float_as_uint(lacc), lb2 = la;
    asm("v_permlane32_swap_b32 %0, %1" : "+v"(la), "+v"(lb2));
    const float ltot = __uint_as_float(la) + __uint_as_float(lb2);

    __syncthreads();                               // all buf reads done
    float* lsh = (float*)lds + wave * 32;          // overlay buffer 0
    if (hi == 0) lsh[ln] = 1.0f / ltot;
    __syncthreads();

    short* ab = attn + (size_t)b * T_ * E_ + h * D_;
#pragma unroll
    for (int r = 0; r < 16; ++r) {
        const int qrow = (r & 3) + ((r >> 2) << 3) + (hi << 2);
        const float iv = lsh[qrow];
        const size_t base = (size_t)(q0w + qrow) * E_;
        ab[base + ln]      = f2bf(O0[r] * iv);
        ab[base + 32 + ln] = f2bf(O1[r] * iv);
    }
}

// ---------------------------------------------------------------------------
extern "C" void kernel_launch(void* const* d_in, const int* in_sizes, int n_in,
                              void* d_out, int out_size, void* d_ws, size_t ws_size,
                              hipStream_t stream) {
    const float* x    = (const float*)d_in[0];
    const float* mask = (const float*)d_in[1];
    const float* Wq   = (const float*)d_in[2];
    const float* Wk   = (const float*)d_in[3];
    const float* Wv   = (const float*)d_in[4];
    const float* Wo   = (const float*)d_in[5];
    const float* bo   = (const float*)d_in[6];
    float* out        = (float*)d_out;

    const size_t S = (size_t)M_ * E_;              // 8.4M elems
    char* ws = (char*)d_ws;
    short* xb   = (short*)ws;                      // bf16 x; reused as attn
    short* qb   = (short*)(ws + S * 2);
    short* kb   = (short*)(ws + S * 4);
    short* vtb  = (short*)(ws + S * 6);            // V stored transposed by MODE0
    short* Wt   = (short*)(ws + S * 8);
    short* Wob  = (short*)(ws + S * 8 + (size_t)3 * 1024 * 1024 * 2);
    float* bias = (float*)(ws + S * 8 + (size_t)4 * 1024 * 1024 * 2);
    short* attnb = xb;

    conv_bf16<<<dim3(M_ * E_ / 1024), 256, 0, stream>>>(x, xb);
    conv_bf16<<<dim3(E_ * E_ / 1024), 256, 0, stream>>>(Wo, Wob);
    wtrans<<<dim3(E_ / 64, H_, 3), 256, 0, stream>>>(Wq, Wk, Wv, Wt);
    bias_prep<<<dim3(B_ * T_ / 256), 256, 0, stream>>>(mask, bias);

    mfma_gemm<0><<<dim3(M_ / 256, 3 * E_ / 128), 512, 0, stream>>>(
        xb, Wt, qb, kb, vtb, nullptr, nullptr);

    flash_attn7<<<dim3(H_, B_, 16), 256, 0, stream>>>(qb, kb, vtb, bias, attnb);

    mfma_gemm<1><<<dim3(M_ / 256, E_ / 128), 512, 0, stream>>>(
        attnb, Wob, nullptr, nullptr, nullptr, out, bo);
}

// Round 8
// 234.274 us; speedup vs baseline: 1.0973x; 1.0140x over previous
//
#include <hip/hip_runtime.h>
#include <hip/hip_bf16.h>

#define B_ 4
#define T_ 2048
#define E_ 1024
#define H_ 16
#define D_ 64
#define M_ (B_*T_)   // 8192 rows

typedef short bf16x8 __attribute__((ext_vector_type(8)));
typedef float f32x4  __attribute__((ext_vector_type(4)));
typedef float f32x16 __attribute__((ext_vector_type(16)));

__device__ __forceinline__ short f2bf(float f) {
    __hip_bfloat16 h = __float2bfloat16(f);
    return *reinterpret_cast<short*>(&h);
}

__device__ __forceinline__ void async_ld16(const void* g, void* l) {
    __builtin_amdgcn_global_load_lds(
        (const __attribute__((address_space(1))) unsigned int*)g,
        (__attribute__((address_space(3))) unsigned int*)l, 16, 0, 0);
}

// ---------------------------------------------------------------------------
// Fused prep kernel (R8): one dispatch replaces conv_bf16 x2, wtrans,
// bias_prep (all independent; branch is wave-uniform per block).
//   blocks [0,8192)      : x fp32 -> bf16
//   blocks [8192,9216)   : Wo fp32 -> bf16
//   blocks [9216,9984)   : Wq/Wk/Wv transpose -> Wt bf16 [3*1024 n][1024 e]
//   blocks [9984,10016)  : mask -> exp2-folded additive bias (static max m=6)
// ---------------------------------------------------------------------------
__global__ __launch_bounds__(256) void prep_fused(
        const float* __restrict__ x,   const float* __restrict__ Wo,
        const float* __restrict__ Wq,  const float* __restrict__ Wk,
        const float* __restrict__ Wv,  const float* __restrict__ mask,
        short* __restrict__ xb, short* __restrict__ Wob,
        short* __restrict__ Wt, float* __restrict__ bias) {
    __shared__ float tile[64][65];
    const int bi  = blockIdx.x;
    const int tid = threadIdx.x;

    if (bi < 9216) {                               // elementwise fp32->bf16
        const float* src = (bi < 8192) ? x : Wo;
        short* dst       = (bi < 8192) ? xb : Wob;
        const int i = ((bi < 8192) ? bi : (bi - 8192)) * 256 + tid;
        float4 v = ((const float4*)src)[i];
        short4 o = make_short4(f2bf(v.x), f2bf(v.y), f2bf(v.z), f2bf(v.w));
        ((short4*)dst)[i] = o;
    } else if (bi < 9984) {                        // weight transpose
        const int idx = bi - 9216;
        const int which = idx >> 8;                // 0..2
        const int h  = (idx & 255) >> 4;
        const int e0 = (idx & 15) * 64;
        const float* __restrict__ W = (which == 0) ? Wq : (which == 1) ? Wk : Wv;
#pragma unroll
        for (int r = 0; r < 4; ++r) {
            int lin = tid + r * 256;
            int er = lin >> 4, c4 = (lin & 15) * 4;
            float4 v = *(const float4*)(W + ((size_t)h * E_ + e0 + er) * D_ + c4);
            tile[er][c4 + 0] = v.x; tile[er][c4 + 1] = v.y;
            tile[er][c4 + 2] = v.z; tile[er][c4 + 3] = v.w;
        }
        __syncthreads();
#pragma unroll
        for (int r = 0; r < 4; ++r) {
            int lin = tid + r * 256;
            int dr = lin >> 4, j4 = (lin & 15) * 4;
            short4 o = make_short4(f2bf(tile[j4 + 0][dr]), f2bf(tile[j4 + 1][dr]),
                                   f2bf(tile[j4 + 2][dr]), f2bf(tile[j4 + 3][dr]));
            *(short4*)(Wt + ((size_t)which * 1024 + h * 64 + dr) * E_ + e0 + j4) = o;
        }
    } else {                                       // bias prep
        const int i = (bi - 9984) * 256 + tid;
        float bm = (1.0f - mask[i]) * -3.402823466e38f;
        bias[i] = fmaf(bm, 1.4426950f, -8.6561700f);
    }
}

// ---------------------------------------------------------------------------
// MFMA GEMM v4 (R8): BK=32, 3 x 24KB LDS buffers (72 KiB) -> TWO blocks/CU
// (16 waves/CU). Inter-block overlap fills each block's vmcnt/barrier drain
// (blocks share no barrier). Single-barrier counted-vmcnt loop (R7-proven):
//   iter k: stage(k+2) [3 loads] -> 8 ds_read -> 16 MFMA (setprio)
//           -> vmcnt(3) -> barrier.
// Race: stage(k+2) -> buf[(k+2)%3] = buf[(k-1)%3]; its readers finished
// before end-of-(k-1) barrier. vmcnt(3) at end of k leaves only tile k+2's
// 3 loads in flight => tile k+1 landed block-wide. Tail: k=30 vmcnt(0).
//
// Buffer (24KB): A[256 rows][32 k] at +0 (16KB), B[128][32] at +16384 (8KB).
// Row = 64B = 4 chunks; chunk swizzle g = src ^ ((row>>1)&3) (involution,
// both sides; even-row lanes cover all 4 slots -> <=2-way, free per m136).
//
// MODE 0: q/k bf16 [B,H,T,D] scatter (q pre-scaled 1/sqrt(D)*log2e);
//         V TRANSPOSED [B,H,D,T].  Grid (32, 24).
// MODE 1: fp32 [M][E] + bias.      Grid (32, 8).
// ---------------------------------------------------------------------------
template <int MODE>
__global__ __launch_bounds__(512, 4) void mfma_gemm(
        const short* __restrict__ A,
        const short* __restrict__ Bt,
        short* __restrict__ qo, short* __restrict__ ko, short* __restrict__ vo,
        float* __restrict__ Cout, const float* __restrict__ bo) {
    __shared__ __align__(16) char lds[3 * 24576];   // 72 KiB -> 2 blocks/CU

    const int tid  = threadIdx.x;
    const int wave = tid >> 6, lane = tid & 63;
    const int c = lane & 15, quad = lane >> 4;
    const int wm = wave >> 1, wn = wave & 1;        // 4M x 2N
    const int m0 = blockIdx.x * 256;
    const int n0 = blockIdx.y * 128;

    // staging coords: chunk = tid (A rows 0-127), tid+512 (A rows 128-255),
    // tid (B rows 0-127). row = chunk>>2, slot g = chunk&3, src cc = g^((row>>1)&3)
    const int ar = tid >> 2;
    const int ag = (tid & 3) ^ ((tid >> 3) & 3);

    // fragment read byte-offsets within a buffer
    int aoff[4], boff[4];
#pragma unroll
    for (int mi = 0; mi < 4; ++mi) {
        int row = wm * 64 + mi * 16 + c;
        aoff[mi] = row * 64 + ((quad ^ ((row >> 1) & 3)) << 4);
    }
#pragma unroll
    for (int ni = 0; ni < 4; ++ni) {
        int row = wn * 64 + ni * 16 + c;
        boff[ni] = 16384 + row * 64 + ((quad ^ ((row >> 1) & 3)) << 4);
    }

    f32x4 acc[4][4] = {};

#define STG(bufb, k0v) do {                                                  \
        async_ld16(A  + (size_t)(m0 + ar) * 1024 + (k0v) + ag * 8,           \
                   lds + (bufb) + wave * 1024);                              \
        async_ld16(A  + (size_t)(m0 + 128 + ar) * 1024 + (k0v) + ag * 8,     \
                   lds + (bufb) + 8192 + wave * 1024);                       \
        async_ld16(Bt + (size_t)(n0 + ar) * 1024 + (k0v) + ag * 8,           \
                   lds + (bufb) + 16384 + wave * 1024);                      \
    } while (0)

    // prologue: stage K-tiles 0 and 1 (3 loads each)
    STG(0, 0);
    STG(24576, 32);
    asm volatile("s_waitcnt vmcnt(3)" ::: "memory");   // K-tile 0 landed
    __builtin_amdgcn_s_barrier();

    int rbase = 0;
#pragma unroll 1
    for (int k = 0; k < 32; ++k) {
        const char* rb = lds + rbase;
        const int wbase = (rbase == 0) ? 49152 : rbase - 24576;

        if (k < 30) STG(wbase, (k + 2) * 32);

        bf16x8 a_[4], b_[4];
#pragma unroll
        for (int mi = 0; mi < 4; ++mi)
            a_[mi] = *(const bf16x8*)(rb + aoff[mi]);
#pragma unroll
        for (int ni = 0; ni < 4; ++ni)
            b_[ni] = *(const bf16x8*)(rb + boff[ni]);

        __builtin_amdgcn_s_setprio(1);
#pragma unroll
        for (int mi = 0; mi < 4; ++mi)
#pragma unroll
            for (int ni = 0; ni < 4; ++ni)
                acc[mi][ni] = __builtin_amdgcn_mfma_f32_16x16x32_bf16(
                    a_[mi], b_[ni], acc[mi][ni], 0, 0, 0);
        __builtin_amdgcn_s_setprio(0);

        if (k < 30)       asm volatile("s_waitcnt vmcnt(3)" ::: "memory");
        else if (k == 30) asm volatile("s_waitcnt vmcnt(0)" ::: "memory");
        if (k < 31) __builtin_amdgcn_s_barrier();

        rbase = (rbase == 49152) ? 0 : rbase + 24576;
    }
#undef STG

    if (MODE == 0) {
        const int which = n0 >> 10;
        const int nb = n0 & 1023;
        if (which == 2) {
            // V: store transposed [b,h,d,t], vectorized short4 along t
#pragma unroll
            for (int mi = 0; mi < 4; ++mi) {
                const int m = m0 + wm * 64 + mi * 16 + quad * 4;
                const int b = m >> 11, t = m & 2047;
#pragma unroll
                for (int ni = 0; ni < 4; ++ni) {
                    const int n = nb + wn * 64 + ni * 16 + c;
                    const int h = n >> 6, d = n & 63;
                    short4 s4 = make_short4(f2bf(acc[mi][ni][0]), f2bf(acc[mi][ni][1]),
                                            f2bf(acc[mi][ni][2]), f2bf(acc[mi][ni][3]));
                    *(short4*)(vo + (((size_t)b * H_ + h) * D_ + d) * T_ + t) = s4;
                }
            }
        } else {
            short* __restrict__ outp = (which == 0) ? qo : ko;
            // q pre-scaled by 1/sqrt(D)*log2(e) so flash uses exp2(S + bias)
            const float sc = (which == 0) ? 0.18033688f : 1.0f;
#pragma unroll
            for (int mi = 0; mi < 4; ++mi) {
#pragma unroll
                for (int i = 0; i < 4; ++i) {
                    const int m = m0 + wm * 64 + mi * 16 + quad * 4 + i;
                    const int b = m >> 11, t = m & 2047;
#pragma unroll
                    for (int ni = 0; ni < 4; ++ni) {
                        const int n = nb + wn * 64 + ni * 16 + c;
                        const int h = n >> 6, d = n & 63;
                        outp[(((size_t)b * H_ + h) * T_ + t) * D_ + d] =
                            f2bf(acc[mi][ni][i] * sc);
                    }
                }
            }
        }
    } else {
#pragma unroll
        for (int mi = 0; mi < 4; ++mi) {
#pragma unroll
            for (int i = 0; i < 4; ++i) {
                const int m = m0 + wm * 64 + mi * 16 + quad * 4 + i;
#pragma unroll
                for (int ni = 0; ni < 4; ++ni) {
                    const int n = n0 + wn * 64 + ni * 16 + c;
                    Cout[(size_t)m * E_ + n] = acc[mi][ni][i] + bo[n];
                }
            }
        }
    }
}

// ---------------------------------------------------------------------------
// Flash attention v7 (unchanged from R7): 4-wave blocks, 128-row q blocks,
// 4 blocks/CU, 4-buffer depth-2 counted-vmcnt pipeline, in-register softmax.
// ---------------------------------------------------------------------------
__global__ __launch_bounds__(256, 4) void flash_attn7(
        const short* __restrict__ qg,
        const short* __restrict__ kg,
        const short* __restrict__ vtg,
        const float* __restrict__ biasg,
        short* __restrict__ attn) {
    const int h = blockIdx.x, b = blockIdx.y;
    const int kb = 15 - blockIdx.z;                // 128-row q block, heavy first
    const int tid  = threadIdx.x;
    const int wave = tid >> 6, lane = tid & 63;
    const int ln = lane & 31, hi = lane >> 5;
    const int q0w = kb * 128 + wave * 32;          // this wave's 32 q rows
    const int mytile = 4 * kb + wave;              // wave's diagonal tile
    const int nt = 4 * kb + 4;

    __shared__ __align__(16) char lds[40960];

    const size_t bh = (size_t)b * H_ + h;
    const short* qbh  = qg  + bh * (size_t)T_ * D_;
    const short* kbh  = kg  + bh * (size_t)T_ * D_;
    const short* vtbh = vtg + bh * (size_t)D_ * T_;
    const float* biasb = biasg + (size_t)b * T_;

    // staging coords: each thread stages ONE K chunk and ONE V chunk per tile
    const int ks = tid >> 3, kgs = (tid & 7) ^ (ks & 7);        // K row / src chunk
    const int vd = tid >> 2, vgs = ((tid & 3) - (vd >> 1)) & 3; // V row / src chunk

    // swizzled LDS read offsets (add (tt&3)*8192 at use)
    int kaddr[4];
#pragma unroll
    for (int kc = 0; kc < 4; ++kc)
        kaddr[kc] = ln * 128 + ((((kc << 1) + hi) ^ (ln & 7)) << 4);
    int vaddr[4];                                  // [dh*2 + kc2]
#pragma unroll
    for (int dh = 0; dh < 2; ++dh)
#pragma unroll
        for (int kc2 = 0; kc2 < 2; ++kc2) {
            int d = dh * 32 + ln;
            vaddr[dh * 2 + kc2] =
                4096 + d * 64 + (((((kc2 << 1) + hi) + (d >> 1)) & 3) << 4);
        }

    // Q fragments (B operand of S^T): col=q=ln, k = kc*16 + hi*8 + e
    bf16x8 qf[4];
#pragma unroll
    for (int kc = 0; kc < 4; ++kc)
        qf[kc] = *(const bf16x8*)(qbh + (size_t)(q0w + ln) * D_ + kc * 16 + hi * 8);

    // stage bias[0..2047] -> LDS once (8KB: 256 threads x 16B x 2 rounds)
#pragma unroll
    for (int r = 0; r < 2; ++r)
        async_ld16(biasb + r * 1024 + tid * 4,
                   lds + 32768 + r * 4096 + wave * 1024);

#define STAGE_T(tt2) do {                                                   \
        const int _s0 = (tt2) << 5;                                         \
        const int _bb = ((tt2) & 3) * 8192;                                 \
        async_ld16(kbh + (size_t)(_s0 + ks) * D_ + (kgs << 3),              \
                   lds + _bb + wave * 1024);                                \
        async_ld16(vtbh + (size_t)vd * T_ + _s0 + (vgs << 3),               \
                   lds + _bb + 4096 + wave * 1024);                         \
    } while (0)

    STAGE_T(0);
    STAGE_T(1);

    f32x16 O0 = {}, O1 = {};
    float lacc = 0.0f;

    for (int tt = 0; tt < nt; ++tt) {
        if (tt + 2 < nt) STAGE_T(tt + 2);
        const int rem = nt - 1 - tt;               // staged tiles beyond tt
        if (rem >= 2)      asm volatile("s_waitcnt vmcnt(4)" ::: "memory");
        else if (rem == 1) asm volatile("s_waitcnt vmcnt(2)" ::: "memory");
        else               asm volatile("s_waitcnt vmcnt(0)" ::: "memory");
        __builtin_amdgcn_s_barrier();              // tile tt landed everywhere

        if (tt <= mytile) {
            const int s0 = tt << 5;
            const int bb = (tt & 3) * 8192;

            // bias for the 16 s-rows (broadcast ds_read, uniform addr per hi)
            f32x4 b4[4];
#pragma unroll
            for (int g = 0; g < 4; ++g)
                b4[g] = *(const f32x4*)(lds + 32768 + (s0 + g * 8 + hi * 4) * 4);

            // S^T = K . Q^T  (A=K from LDS, B=Q regs); q pre-scaled
            f32x16 S = {};
            __builtin_amdgcn_s_setprio(1);
#pragma unroll
            for (int kc = 0; kc < 4; ++kc) {
                bf16x8 ka = *(const bf16x8*)(lds + bb + kaddr[kc]);
                S = __builtin_amdgcn_mfma_f32_32x32x16_bf16(ka, qf[kc], S, 0, 0, 0);
            }
            __builtin_amdgcn_s_setprio(0);

            float p[16];
#pragma unroll
            for (int r = 0; r < 16; ++r) {
                float bb2 = ((const float*)&b4[r >> 2])[r & 3];
                p[r] = __builtin_amdgcn_exp2f(S[r] + bb2);
            }
            if (tt == mytile) {                    // causal mask on diagonal
#pragma unroll
                for (int r = 0; r < 16; ++r)
                    if (((r & 3) + ((r >> 2) << 3) + (hi << 2)) > ln)
                        p[r] = 0.0f;
            }
            // l partial (tree)
            {
                float t0 = (p[0] + p[1]) + (p[2] + p[3]);
                float t1 = (p[4] + p[5]) + (p[6] + p[7]);
                float t2s = (p[8] + p[9]) + (p[10] + p[11]);
                float t3 = (p[12] + p[13]) + (p[14] + p[15]);
                lacc += (t0 + t1) + (t2s + t3);
            }

            // pack to bf16 (HW cvt_pk) + permlane32_swap -> PV A-frags (T12)
            unsigned int u0, u1, u2, u3, u4, u5, u6, u7;
            asm("v_cvt_pk_bf16_f32 %0, %1, %2" : "=v"(u0) : "v"(p[0]),  "v"(p[1]));
            asm("v_cvt_pk_bf16_f32 %0, %1, %2" : "=v"(u1) : "v"(p[2]),  "v"(p[3]));
            asm("v_cvt_pk_bf16_f32 %0, %1, %2" : "=v"(u2) : "v"(p[4]),  "v"(p[5]));
            asm("v_cvt_pk_bf16_f32 %0, %1, %2" : "=v"(u3) : "v"(p[6]),  "v"(p[7]));
            asm("v_cvt_pk_bf16_f32 %0, %1, %2" : "=v"(u4) : "v"(p[8]),  "v"(p[9]));
            asm("v_cvt_pk_bf16_f32 %0, %1, %2" : "=v"(u5) : "v"(p[10]), "v"(p[11]));
            asm("v_cvt_pk_bf16_f32 %0, %1, %2" : "=v"(u6) : "v"(p[12]), "v"(p[13]));
            asm("v_cvt_pk_bf16_f32 %0, %1, %2" : "=v"(u7) : "v"(p[14]), "v"(p[15]));
            asm("v_permlane32_swap_b32 %0, %1" : "+v"(u0), "+v"(u2));
            asm("v_permlane32_swap_b32 %0, %1" : "+v"(u1), "+v"(u3));
            asm("v_permlane32_swap_b32 %0, %1" : "+v"(u4), "+v"(u6));
            asm("v_permlane32_swap_b32 %0, %1" : "+v"(u5), "+v"(u7));
            union { unsigned int w[4]; bf16x8 v; } pa0, pa1;
            pa0.w[0] = u0; pa0.w[1] = u1; pa0.w[2] = u2; pa0.w[3] = u3;
            pa1.w[0] = u4; pa1.w[1] = u5; pa1.w[2] = u6; pa1.w[3] = u7;

            // O += P . V  (B=V^T slices from LDS)
            bf16x8 v00 = *(const bf16x8*)(lds + bb + vaddr[0]);
            bf16x8 v01 = *(const bf16x8*)(lds + bb + vaddr[1]);
            bf16x8 v10 = *(const bf16x8*)(lds + bb + vaddr[2]);
            bf16x8 v11 = *(const bf16x8*)(lds + bb + vaddr[3]);
            __builtin_amdgcn_s_setprio(1);
            O0 = __builtin_amdgcn_mfma_f32_32x32x16_bf16(pa0.v, v00, O0, 0, 0, 0);
            O0 = __builtin_amdgcn_mfma_f32_32x32x16_bf16(pa1.v, v01, O0, 0, 0, 0);
            O1 = __builtin_amdgcn_mfma_f32_32x32x16_bf16(pa0.v, v10, O1, 0, 0, 0);
            O1 = __builtin_amdgcn_mfma_f32_32x32x16_bf16(pa1.v, v11, O1, 0, 0, 0);
            __builtin_amdgcn_s_setprio(0);
        }
    }
#undef STAGE_T

    // ---- epilogue: combine l across hi-halves, normalize, store -----------
    unsigned int la = __float_as_uint(lacc), lb2 = la;
    asm("v_permlane32_swap_b32 %0, %1" : "+v"(la), "+v"(lb2));
    const float ltot = __uint_as_float(la) + __uint_as_float(lb2);

    __syncthreads();                               // all buf reads done
    float* lsh = (float*)lds + wave * 32;          // overlay buffer 0
    if (hi == 0) lsh[ln] = 1.0f / ltot;
    __syncthreads();

    short* ab = attn + (size_t)b * T_ * E_ + h * D_;
#pragma unroll
    for (int r = 0; r < 16; ++r) {
        const int qrow = (r & 3) + ((r >> 2) << 3) + (hi << 2);
        const float iv = lsh[qrow];
        const size_t base = (size_t)(q0w + qrow) * E_;
        ab[base + ln]      = f2bf(O0[r] * iv);
        ab[base + 32 + ln] = f2bf(O1[r] * iv);
    }
}

// ---------------------------------------------------------------------------
extern "C" void kernel_launch(void* const* d_in, const int* in_sizes, int n_in,
                              void* d_out, int out_size, void* d_ws, size_t ws_size,
                              hipStream_t stream) {
    const float* x    = (const float*)d_in[0];
    const float* mask = (const float*)d_in[1];
    const float* Wq   = (const float*)d_in[2];
    const float* Wk   = (const float*)d_in[3];
    const float* Wv   = (const float*)d_in[4];
    const float* Wo   = (const float*)d_in[5];
    const float* bo   = (const float*)d_in[6];
    float* out        = (float*)d_out;

    const size_t S = (size_t)M_ * E_;              // 8.4M elems
    char* ws = (char*)d_ws;
    short* xb   = (short*)ws;                      // bf16 x; reused as attn
    short* qb   = (short*)(ws + S * 2);
    short* kb   = (short*)(ws + S * 4);
    short* vtb  = (short*)(ws + S * 6);            // V stored transposed by MODE0
    short* Wt   = (short*)(ws + S * 8);
    short* Wob  = (short*)(ws + S * 8 + (size_t)3 * 1024 * 1024 * 2);
    float* bias = (float*)(ws + S * 8 + (size_t)4 * 1024 * 1024 * 2);
    short* attnb = xb;

    prep_fused<<<dim3(10016), 256, 0, stream>>>(
        x, Wo, Wq, Wk, Wv, mask, xb, Wob, Wt, bias);

    mfma_gemm<0><<<dim3(M_ / 256, 3 * E_ / 128), 512, 0, stream>>>(
        xb, Wt, qb, kb, vtb, nullptr, nullptr);

    flash_attn7<<<dim3(H_, B_, 16), 256, 0, stream>>>(qb, kb, vtb, bias, attnb);

    mfma_gemm<1><<<dim3(M_ / 256, E_ / 128), 512, 0, stream>>>(
        attnb, Wob, nullptr, nullptr, nullptr, out, bo);
}